// Round 7
// baseline (546.439 us; speedup 1.0000x reference)
//
#include <hip/hip_runtime.h>

#define BB 4
#define CC 96
#define HH 64
#define WW 64
#define LL 4096
#define KK 3
#define RR 6
#define NN 16

__device__ __forceinline__ float geluf(float x){
    return 0.5f * x * (1.0f + erff(x * 0.70710678118654752f));
}
__device__ __forceinline__ float softplusf(float x){
    return fmaxf(x, 0.0f) + log1pf(expf(-fabsf(x)));
}
__device__ __forceinline__ float sigmoidf(float x){
    return 1.0f / (1.0f + expf(-x));
}

// ---------------- Kernel A: per-(b,c) spatial mean ----------------
__global__ __launch_bounds__(256) void k_mean(const float* __restrict__ x, float* __restrict__ xc){
    int bc = blockIdx.x; // 0..B*C-1
    const float* p = x + (size_t)bc * LL;
    float s = 0.f;
    for (int i = threadIdx.x; i < LL; i += 256) s += p[i];
    __shared__ float red[256];
    red[threadIdx.x] = s; __syncthreads();
    for (int st = 128; st > 0; st >>= 1){
        if (threadIdx.x < st) red[threadIdx.x] += red[threadIdx.x + st];
        __syncthreads();
    }
    if (threadIdx.x == 0) xc[bc] = red[0] * (1.0f / LL);
}

// ---------------- Kernel B: channel-attention MLP ----------------
__global__ __launch_bounds__(128) void k_ca(const float* __restrict__ xc,
                     const float* __restrict__ w1, const float* __restrict__ b1,
                     const float* __restrict__ w2, const float* __restrict__ b2,
                     float* __restrict__ ca){
    int b = blockIdx.x;
    int t = threadIdx.x;
    __shared__ float hid[CC/16];
    if (t < CC/16){
        float a = b1[t];
        for (int d = 0; d < CC; d++) a += w1[t*CC + d] * xc[b*CC + d];
        hid[t] = geluf(a);
    }
    __syncthreads();
    if (t < CC){
        float a = b2[t];
        #pragma unroll
        for (int i = 0; i < CC/16; i++) a += w2[t*(CC/16) + i] * hid[i];
        ca[b*CC + t] = sigmoidf(a);
    }
}

// ---------------- Kernel C: depthwise 9x9 conv + bias, scaled by ca ----------------
__global__ __launch_bounds__(256) void k_conv(const float* __restrict__ x, const float* __restrict__ w,
                       const float* __restrict__ bias, const float* __restrict__ ca,
                       float* __restrict__ x1){
    int gid = blockIdx.x * 256 + threadIdx.x; // B*C*L
    int l = gid & (LL-1); int bc = gid >> 12;
    int c = bc % CC; int b = bc / CC;
    int h = l >> 6, wq = l & 63;
    const float* xp = x + (size_t)bc * LL;
    const float* wp = w + c * 81;
    float acc = 0.f;
    #pragma unroll
    for (int ky = 0; ky < 9; ky++){
        int yy = h + ky - 4;
        if (yy < 0 || yy >= HH) continue;
        #pragma unroll
        for (int kx = 0; kx < 9; kx++){
            int xx = wq + kx - 4;
            if (xx < 0 || xx >= WW) continue;
            acc += xp[yy*WW + xx] * wp[ky*9 + kx];
        }
    }
    x1[gid] = (acc + bias[c]) * ca[b*CC + c];
}

// ---------------- Kernel D: rpe resize 7x7 -> 64x64 (b-independent) ----------------
__global__ __launch_bounds__(256) void k_rpe(const float* __restrict__ t, float* __restrict__ out){
    int gid = blockIdx.x * 256 + threadIdx.x; // C*L
    int l = gid & (LL-1); int c = gid >> 12;
    int h = l >> 6, w = l & 63;
    float sy = fmaxf((h + 0.5f) * (7.0f/64.0f) - 0.5f, 0.f);
    float sx = fmaxf((w + 0.5f) * (7.0f/64.0f) - 0.5f, 0.f);
    int y0 = (int)floorf(sy); int x0 = (int)floorf(sx);
    float wy = sy - (float)y0, wx = sx - (float)x0;
    int y1 = min(y0 + 1, 6), x1i = min(x0 + 1, 6);
    const float* tp = t + c * 49;
    float r0 = tp[y0*7 + x0] * (1.f - wy) + tp[y1*7 + x0] * wy;
    float r1 = tp[y0*7 + x1i] * (1.f - wy) + tp[y1*7 + x1i] * wy;
    out[gid] = r0 * (1.f - wx) + r1 * wx;
}

// ---------------- Kernel E: LayerNorm(C) + GELU + 1x1 conv -> pos/path ----------------
__global__ __launch_bounds__(256) void k_off(const float* __restrict__ x1,
                      const float* __restrict__ g, const float* __restrict__ bta,
                      const float* __restrict__ w2,
                      float* __restrict__ posy, float* __restrict__ posx, float* __restrict__ path){
    int gid = blockIdx.x * 256 + threadIdx.x; // B*L
    int l = gid & (LL-1); int b = gid >> 12;
    const float* p = x1 + (size_t)b * CC * LL + l;
    float s = 0.f, ss = 0.f;
    for (int c = 0; c < CC; c++){
        float v = p[(size_t)c * LL];
        s += v; ss += v * v;
    }
    float m = s * (1.0f / CC);
    float var = ss * (1.0f / CC) - m * m;
    float rstd = rsqrtf(var + 1e-5f);
    float a0 = 0.f, a1 = 0.f, a2 = 0.f;
    for (int c = 0; c < CC; c++){
        float v = p[(size_t)c * LL];
        float xn = (v - m) * rstd * g[c] + bta[c];
        float xg = geluf(xn);
        a0 += w2[c] * xg;
        a1 += w2[CC + c] * xg;
        a2 += w2[2*CC + c] * xg;
    }
    int h = l >> 6, w = l & 63;
    float ry = (2*h + 1) * (1.0f/63.0f) - 1.0f;
    float rx = (2*w + 1) * (1.0f/63.0f) - 1.0f;
    posy[gid] = tanhf(a0) * (1.0f/63.0f) + ry;
    posx[gid] = tanhf(a1) * (1.0f/63.0f) + rx;
    path[gid] = tanhf(a2) + ((l + 0.5f) * (2.0f/4095.0f) - 1.0f);
}

// ---------------- Kernel F: hybrid register/shuffle/LDS stable bitonic argsort ----------------
typedef unsigned long long u64s;
__device__ __forceinline__ u64s shflx64(u64s x, int m){
    int lo = __shfl_xor((int)(unsigned)x, m);
    int hi = __shfl_xor((int)(unsigned)(x >> 32), m);
    return ((u64s)(unsigned)hi << 32) | (unsigned)lo;
}
__device__ __forceinline__ void cex(u64s& a, u64s& b, bool up){
    u64s mn = a < b ? a : b;
    u64s mx = a < b ? b : a;
    a = up ? mn : mx;
    b = up ? mx : mn;
}
__global__ __launch_bounds__(1024) void k_sort(const float* __restrict__ path,
                                               int* __restrict__ idx, int* __restrict__ inv){
    int b = blockIdx.x;
    int t = threadIdx.x;
    __shared__ u64s lds[LL];
    u64s v[4];
    #pragma unroll
    for (int r = 0; r < 4; r++){
        int e = t*4 + r;
        unsigned u = __float_as_uint(path[b*LL + e]);
        u ^= (u >> 31) ? 0xFFFFFFFFu : 0x80000000u;   // monotonic float->uint
        v[r] = ((u64s)u << 32) | (unsigned)e;
    }
    for (int kk = 2; kk <= LL; kk <<= 1){
        for (int j = kk >> 1; j > 0; j >>= 1){
            if (j >= 256){
                __syncthreads();
                #pragma unroll
                for (int r = 0; r < 4; r++) lds[t*4 + r] = v[r];
                __syncthreads();
                #pragma unroll
                for (int r = 0; r < 4; r++){
                    int e = t*4 + r;
                    u64s pv = lds[e ^ j];
                    bool up    = ((e & kk) == 0);
                    bool lower = ((e & j) == 0);
                    u64s mn = v[r] < pv ? v[r] : pv;
                    u64s mx = v[r] < pv ? pv : v[r];
                    v[r] = (up == lower) ? mn : mx;
                }
            } else if (j >= 4){
                int m = j >> 2;
                #pragma unroll
                for (int r = 0; r < 4; r++){
                    u64s pv = shflx64(v[r], m);
                    bool up    = (((t*4 + r) & kk) == 0);
                    bool lower = ((t & m) == 0);
                    u64s mn = v[r] < pv ? v[r] : pv;
                    u64s mx = v[r] < pv ? pv : v[r];
                    v[r] = (up == lower) ? mn : mx;
                }
            } else if (j == 2){
                bool up = (((t*4) & kk) == 0);
                cex(v[0], v[2], up);
                cex(v[1], v[3], up);
            } else { // j == 1
                if (kk == 2){
                    cex(v[0], v[1], true);
                    cex(v[2], v[3], false);
                } else {
                    bool up = (((t*4) & kk) == 0);
                    cex(v[0], v[1], up);
                    cex(v[2], v[3], up);
                }
            }
        }
    }
    #pragma unroll
    for (int r = 0; r < 4; r++){
        int e = t*4 + r;
        int id = (int)(unsigned)(v[r] & 0xFFFFFFFFu);
        idx[b*LL + e] = id;
        inv[b*LL + id] = e;
    }
}

// ---------------- bilinear sample, zero padding ----------------
__device__ __forceinline__ float bilin0(const float* __restrict__ img, float gx, float gy){
    float fx = (gx + 1.f) * 31.5f;   // (W-1)/2 = 31.5
    float fy = (gy + 1.f) * 31.5f;
    float x0f = floorf(fx), y0f = floorf(fy);
    float wx = fx - x0f, wy = fy - y0f;
    int x0 = (int)x0f, y0 = (int)y0f;
    float acc = 0.f;
    bool vx0 = (x0 >= 0) & (x0 < WW), vx1 = (x0+1 >= 0) & (x0+1 < WW);
    bool vy0 = (y0 >= 0) & (y0 < HH), vy1 = (y0+1 >= 0) & (y0+1 < HH);
    if (vy0 & vx0) acc += img[y0*WW + x0]       * (1.f-wx) * (1.f-wy);
    if (vy0 & vx1) acc += img[y0*WW + x0+1]     * wx       * (1.f-wy);
    if (vy1 & vx0) acc += img[(y0+1)*WW + x0]   * (1.f-wx) * wy;
    if (vy1 & vx1) acc += img[(y0+1)*WW + x0+1] * wx       * wy;
    return acc;
}

// ---------------- Kernel S: x grid-sample + rpe grid-sample -> xd ----------------
__global__ __launch_bounds__(256) void k_sample(const float* __restrict__ x, const float* __restrict__ rpe,
                         const float* __restrict__ posy, const float* __restrict__ posx,
                         float* __restrict__ xd){
    int gid = blockIdx.x * 256 + threadIdx.x; // B*C*L
    int l = gid & (LL-1); int bc = gid >> 12;
    int b = bc / CC; int c = bc % CC;
    float gy = posy[b*LL + l], gx = posx[b*LL + l];
    float v = bilin0(x + (size_t)bc * LL, gx, gy);
    int h = l >> 6, w = l & 63;
    float ky = h * (128.0f/3969.0f) - 1.0f;  // linspace(0,64,64)/63*2-1
    float kx = w * (128.0f/3969.0f) - 1.0f;
    float v2 = bilin0(rpe + (size_t)c * LL, (kx - gx) * 0.5f, (ky - gy) * 0.5f);
    xd[gid] = v + v2;
}

// ---------------- Kernel G: projection, 4 waves/block over channel quarters ----------------
// Block = 256 thr = 4 waves; all waves share the same 64 l's, wave w handles
// channels [24w, 24w+24). Partial 38-accs reduced via LDS. B/C stored as
// contiguous float4 per lane. Grid = B*K*64 = 768 blocks x 4 waves -> 3 waves/SIMD.
__global__ __launch_bounds__(256) void k_proj(const float* __restrict__ x, const float* __restrict__ xd,
    const int* __restrict__ indices, const float* __restrict__ xpw, const float* __restrict__ dtw,
    const float* __restrict__ dtb, float* __restrict__ u2, float* __restrict__ dt,
    float* __restrict__ Bst, float* __restrict__ Cst){
    int blk = blockIdx.x;          // B*K*64 blocks
    int ltile = blk & 63; int bk = blk >> 6;
    int k = bk % KK; int b = bk / KK;
    int lane = threadIdx.x & 63;
    int w = threadIdx.x >> 6;      // 0..3
    int l = ltile * 64 + lane;
    int srcl = (k == 0) ? l : (k == 1 ? (LL-1-l) : indices[b*LL + l]);
    const float* xp = (k == 2 ? xd : x) + (size_t)b * CC * LL + srcl;
    const float* __restrict__ Wk = xpw + k*38*CC;

    // wave w: batch-load its 24 channel values (independent, all in flight)
    float v[24];
    #pragma unroll
    for (int j = 0; j < 24; j++) v[j] = xp[(size_t)(w*24 + j) * LL];

    float acc[38];
    #pragma unroll
    for (int i = 0; i < 38; i++) acc[i] = 0.f;
    #pragma unroll
    for (int j = 0; j < 24; j++){
        int d = w*24 + j;
        #pragma unroll
        for (int i = 0; i < 38; i++) acc[i] = fmaf(Wk[i*CC + d], v[j], acc[i]);
    }

    if (k == 2){
        float* up = u2 + (size_t)b * CC * LL + l;
        #pragma unroll
        for (int j = 0; j < 24; j++) up[(size_t)(w*24 + j) * LL] = v[j];
    }

    __shared__ float lds[4*38*64];   // 38.9 KB
    #pragma unroll
    for (int i = 0; i < 38; i++) lds[(w*38 + i)*64 + lane] = acc[i];
    __syncthreads();
    // reduce across waves: wave w handles i % 4 == w, result into w0 slot
    for (int i = w; i < 38; i += 4){
        float r = lds[i*64 + lane] + lds[(38 + i)*64 + lane]
                + lds[(76 + i)*64 + lane] + lds[(114 + i)*64 + lane];
        lds[i*64 + lane] = r;
    }
    __syncthreads();

    size_t base = ((size_t)bk * LL + l) * NN;
    if (w == 0){            // B: 16 contiguous floats per l -> 4 float4
        #pragma unroll
        for (int q4 = 0; q4 < 4; q4++){
            float4 q;
            q.x = lds[(RR + q4*4 + 0)*64 + lane];
            q.y = lds[(RR + q4*4 + 1)*64 + lane];
            q.z = lds[(RR + q4*4 + 2)*64 + lane];
            q.w = lds[(RR + q4*4 + 3)*64 + lane];
            *(float4*)(Bst + base + q4*4) = q;
        }
    } else if (w == 1){     // C
        #pragma unroll
        for (int q4 = 0; q4 < 4; q4++){
            float4 q;
            q.x = lds[(RR + NN + q4*4 + 0)*64 + lane];
            q.y = lds[(RR + NN + q4*4 + 1)*64 + lane];
            q.z = lds[(RR + NN + q4*4 + 2)*64 + lane];
            q.w = lds[(RR + NN + q4*4 + 3)*64 + lane];
            *(float4*)(Cst + base + q4*4) = q;
        }
    }

    float a0 = lds[0*64 + lane], a1 = lds[1*64 + lane], a2 = lds[2*64 + lane];
    float a3 = lds[3*64 + lane], a4 = lds[4*64 + lane], a5 = lds[5*64 + lane];
    const float* __restrict__ Dw = dtw + k*CC*RR;
    const float* __restrict__ Db = dtb + k*CC;
    float* dtp = dt + (size_t)bk * CC * LL + l;
    #pragma unroll
    for (int j = 0; j < 24; j++){
        int d = w*24 + j;
        float sdt = Db[d];
        sdt = fmaf(a0, Dw[d*RR + 0], sdt);
        sdt = fmaf(a1, Dw[d*RR + 1], sdt);
        sdt = fmaf(a2, Dw[d*RR + 2], sdt);
        sdt = fmaf(a3, Dw[d*RR + 3], sdt);
        sdt = fmaf(a4, Dw[d*RR + 4], sdt);
        sdt = fmaf(a5, Dw[d*RR + 5], sdt);
        dtp[(size_t)d * LL] = softplusf(sdt);
    }
}

// ---------------- Kernel H: merged chunked-parallel selective scan ----------------
// One dispatch for all 3 directions: k from blockIdx, if-chain into compile-time
// bodies (constant strides). float4 loads of dt/u (4 t-steps), float4 y stores.
#define ST 32          // segments
#define TT 128         // steps per segment
template<int KIND>
__device__ __forceinline__ void scan_body(int b, int d, const float* __restrict__ usrc,
    const float* __restrict__ dt, const float* __restrict__ Bst, const float* __restrict__ Cst,
    const float* __restrict__ Alog, const float* __restrict__ Ds, float* __restrict__ ys,
    float* sA, float* sB, float* sCin){
    int bk = b * KK + KIND;
    int tid = threadIdx.x;
    int n = tid & 15; int s = tid >> 4;      // s in [0,32)
    int t0 = s * TT;

    float A  = -__expf(Alog[(KIND*CC + d)*NN + n]);
    float Dv = Ds[KIND*CC + d];

    const float* dtp = dt + ((size_t)bk * CC + d) * LL + t0;
    const float* ub = (KIND == 1)
        ? usrc + ((size_t)b*CC + d) * LL + (LL-4-t0)   // float4 window [LL-4-t0-t .. LL-1-t0-t]
        : usrc + ((size_t)b*CC + d) * LL + t0;
    const float* Bp = Bst + ((size_t)bk * LL + t0) * NN + n;
    const float* Cp = Cst + ((size_t)bk * LL + t0) * NN + n;
    float* yp = ys + ((size_t)bk * CC + d) * LL + t0;

    // Phase 1: local segment scan from h=0, track product of a
    float Aprod = 1.f, h = 0.f;
    for (int t = 0; t < TT; t += 4){
        float4 dq = *(const float4*)(dtp + t);
        float4 uq = (KIND == 1) ? *(const float4*)(ub - t) : *(const float4*)(ub + t);
        float u0, u1, u2v, u3;
        if (KIND == 1){ u0 = uq.w; u1 = uq.z; u2v = uq.y; u3 = uq.x; }
        else          { u0 = uq.x; u1 = uq.y; u2v = uq.z; u3 = uq.w; }
        float B0 = Bp[(t+0)*NN], B1 = Bp[(t+1)*NN], B2 = Bp[(t+2)*NN], B3 = Bp[(t+3)*NN];
        float a;
        a = __expf(dq.x * A); Aprod *= a; h = fmaf(a, h, dq.x * u0  * B0);
        a = __expf(dq.y * A); Aprod *= a; h = fmaf(a, h, dq.y * u1  * B1);
        a = __expf(dq.z * A); Aprod *= a; h = fmaf(a, h, dq.z * u2v * B2);
        a = __expf(dq.w * A); Aprod *= a; h = fmaf(a, h, dq.w * u3  * B3);
    }

    // Phase 2: exclusive scan of (Aprod, h) over segments, per chain n
    sA[s*16 + n] = Aprod;
    sB[s*16 + n] = h;
    __syncthreads();
    if (tid < 16){
        float c = 0.f;
        #pragma unroll
        for (int ss = 0; ss < ST; ss++){
            sCin[ss*16 + tid] = c;
            c = fmaf(sA[ss*16 + tid], c, sB[ss*16 + tid]);
        }
    }
    __syncthreads();
    float hc = sCin[s*16 + n];

    // Phase 3: replay with carry-in, emit y as float4
    for (int t = 0; t < TT; t += 4){
        float4 dq = *(const float4*)(dtp + t);
        float4 uq = (KIND == 1) ? *(const float4*)(ub - t) : *(const float4*)(ub + t);
        float u0, u1, u2v, u3;
        if (KIND == 1){ u0 = uq.w; u1 = uq.z; u2v = uq.y; u3 = uq.x; }
        else          { u0 = uq.x; u1 = uq.y; u2v = uq.z; u3 = uq.w; }
        float B0 = Bp[(t+0)*NN], B1 = Bp[(t+1)*NN], B2 = Bp[(t+2)*NN], B3 = Bp[(t+3)*NN];
        float C0 = Cp[(t+0)*NN], C1 = Cp[(t+1)*NN], C2 = Cp[(t+2)*NN], C3 = Cp[(t+3)*NN];
        float a, p;
        float4 yo;
        a = __expf(dq.x * A); hc = fmaf(a, hc, dq.x * u0  * B0); p = hc * C0;
        p += __shfl_xor(p,1); p += __shfl_xor(p,2); p += __shfl_xor(p,4); p += __shfl_xor(p,8);
        yo.x = fmaf(u0, Dv, p);
        a = __expf(dq.y * A); hc = fmaf(a, hc, dq.y * u1  * B1); p = hc * C1;
        p += __shfl_xor(p,1); p += __shfl_xor(p,2); p += __shfl_xor(p,4); p += __shfl_xor(p,8);
        yo.y = fmaf(u1, Dv, p);
        a = __expf(dq.z * A); hc = fmaf(a, hc, dq.z * u2v * B2); p = hc * C2;
        p += __shfl_xor(p,1); p += __shfl_xor(p,2); p += __shfl_xor(p,4); p += __shfl_xor(p,8);
        yo.z = fmaf(u2v, Dv, p);
        a = __expf(dq.w * A); hc = fmaf(a, hc, dq.w * u3  * B3); p = hc * C3;
        p += __shfl_xor(p,1); p += __shfl_xor(p,2); p += __shfl_xor(p,4); p += __shfl_xor(p,8);
        yo.w = fmaf(u3, Dv, p);
        if (n == 0) *(float4*)(yp + t) = yo;
    }
}

__global__ __launch_bounds__(512) void k_scan_all(const float* __restrict__ x, const float* __restrict__ u2,
    const float* __restrict__ dt, const float* __restrict__ Bst, const float* __restrict__ Cst,
    const float* __restrict__ Alog, const float* __restrict__ Ds, float* __restrict__ ys){
    __shared__ float sA[ST*16];
    __shared__ float sB[ST*16];
    __shared__ float sCin[ST*16];
    int blk = blockIdx.x;            // KK*BB*CC
    int k = blk / (BB*CC);
    int r = blk % (BB*CC);
    int d = r % CC; int b = r / CC;
    if (k == 0)      scan_body<0>(b, d, x,  dt, Bst, Cst, Alog, Ds, ys, sA, sB, sCin);
    else if (k == 1) scan_body<1>(b, d, x,  dt, Bst, Cst, Alog, Ds, ys, sA, sB, sCin);
    else             scan_body<2>(b, d, u2, dt, Bst, Cst, Alog, Ds, ys, sA, sB, sCin);
}

// ---------------- Kernel I: combine 3 paths + transpose to (B,L,C) ----------------
__global__ __launch_bounds__(256) void k_comb(const float* __restrict__ ys, const int* __restrict__ inv,
                                              float* __restrict__ out){
    int tile = blockIdx.x & 63; int b = blockIdx.x >> 6;
    int l0 = tile * 64;
    __shared__ float t0[CC * 65];
    __shared__ int invs[64];
    if (threadIdx.x < 64) invs[threadIdx.x] = inv[b*LL + l0 + threadIdx.x];
    __syncthreads();
    const float* y0p = ys + (size_t)(b*KK + 0) * CC * LL;
    const float* y1p = ys + (size_t)(b*KK + 1) * CC * LL;
    const float* y2p = ys + (size_t)(b*KK + 2) * CC * LL;
    for (int it = 0; it < 24; it++){
        int e = it * 256 + threadIdx.x;
        int li = e & 63; int c = e >> 6;
        int l = l0 + li;
        float v = y0p[(size_t)c*LL + l] + y1p[(size_t)c*LL + (LL-1-l)] + y2p[(size_t)c*LL + invs[li]];
        t0[c*65 + li] = v * (1.0f/3.0f);
    }
    __syncthreads();
    for (int it = 0; it < 24; it++){
        int e = it * 256 + threadIdx.x;
        int c = e % CC; int li = e / CC;
        out[((size_t)b*LL + l0 + li) * CC + c] = t0[c*65 + li];
    }
}

extern "C" void kernel_launch(void* const* d_in, const int* in_sizes, int n_in,
                              void* d_out, int out_size, void* d_ws, size_t ws_size,
                              hipStream_t stream){
    const float* x    = (const float*)d_in[0];
    const float* xpw  = (const float*)d_in[1];
    const float* dtw  = (const float*)d_in[2];
    const float* dtb  = (const float*)d_in[3];
    const float* Alog = (const float*)d_in[4];
    const float* Ds   = (const float*)d_in[5];
    const float* c1w  = (const float*)d_in[6];
    const float* c1b  = (const float*)d_in[7];
    const float* ca1w = (const float*)d_in[8];
    const float* ca1b = (const float*)d_in[9];
    const float* ca2w = (const float*)d_in[10];
    const float* ca2b = (const float*)d_in[11];
    const float* lng  = (const float*)d_in[12];
    const float* lnb  = (const float*)d_in[13];
    const float* c2w  = (const float*)d_in[14];
    const float* rpet = (const float*)d_in[15];
    float* out = (float*)d_out;

    float* ws   = (float*)d_ws;
    float* xc   = ws;                      // 384
    float* ca   = xc + 384;                // 384
    float* x1   = ca + 384;                // B*C*L = 1572864
    float* rpe  = x1 + (size_t)BB*CC*LL;   // C*L = 393216
    float* posy = rpe + (size_t)CC*LL;     // B*L
    float* posx = posy + (size_t)BB*LL;
    float* path = posx + (size_t)BB*LL;
    float* xd   = path + (size_t)BB*LL;    // B*C*L
    int*   idx  = (int*)(xd + (size_t)BB*CC*LL);   // B*L ints
    int*   inv  = idx + (size_t)BB*LL;             // B*L ints
    float* u2   = (float*)(inv + (size_t)BB*LL);   // B*C*L
    float* dtA  = u2 + (size_t)BB*CC*LL;           // B*K*C*L = 4718592
    float* Bst  = dtA + (size_t)BB*KK*CC*LL;       // B*K*L*N = 786432
    float* Cst  = Bst + (size_t)BB*KK*LL*NN;
    float* ysA  = Cst + (size_t)BB*KK*LL*NN;       // B*K*C*L

    k_mean  <<<BB*CC, 256, 0, stream>>>(x, xc);
    k_ca    <<<BB, 128, 0, stream>>>(xc, ca1w, ca1b, ca2w, ca2b, ca);
    k_conv  <<<(BB*CC*LL)/256, 256, 0, stream>>>(x, c1w, c1b, ca, x1);
    k_rpe   <<<(CC*LL)/256, 256, 0, stream>>>(rpet, rpe);
    k_off   <<<(BB*LL)/256, 256, 0, stream>>>(x1, lng, lnb, c2w, posy, posx, path);
    k_sort  <<<BB, 1024, 0, stream>>>(path, idx, inv);
    k_sample<<<(BB*CC*LL)/256, 256, 0, stream>>>(x, rpe, posy, posx, xd);
    k_proj  <<<BB*KK*64, 256, 0, stream>>>(x, xd, idx, xpw, dtw, dtb, u2, dtA, Bst, Cst);
    k_scan_all<<<KK*BB*CC, 512, 0, stream>>>(x, u2, dtA, Bst, Cst, Alog, Ds, ysA);
    k_comb  <<<BB*64, 256, 0, stream>>>(ysA, inv, out);
}

// Round 8
// 365.438 us; speedup vs baseline: 1.4953x; 1.4953x over previous
//
#include <hip/hip_runtime.h>

#define BB 4
#define CC 96
#define HH 64
#define WW 64
#define LL 4096
#define KK 3
#define RR 6
#define NN 16

__device__ __forceinline__ float geluf(float x){
    return 0.5f * x * (1.0f + erff(x * 0.70710678118654752f));
}
__device__ __forceinline__ float softplusf(float x){
    return fmaxf(x, 0.0f) + log1pf(expf(-fabsf(x)));
}
__device__ __forceinline__ float sigmoidf(float x){
    return 1.0f / (1.0f + expf(-x));
}

// ---------------- Kernel A: per-(b,c) spatial mean ----------------
__global__ __launch_bounds__(256) void k_mean(const float* __restrict__ x, float* __restrict__ xc){
    int bc = blockIdx.x; // 0..B*C-1
    const float* p = x + (size_t)bc * LL;
    float s = 0.f;
    for (int i = threadIdx.x; i < LL; i += 256) s += p[i];
    __shared__ float red[256];
    red[threadIdx.x] = s; __syncthreads();
    for (int st = 128; st > 0; st >>= 1){
        if (threadIdx.x < st) red[threadIdx.x] += red[threadIdx.x + st];
        __syncthreads();
    }
    if (threadIdx.x == 0) xc[bc] = red[0] * (1.0f / LL);
}

// ---------------- Kernel B: channel-attention MLP ----------------
__global__ __launch_bounds__(128) void k_ca(const float* __restrict__ xc,
                     const float* __restrict__ w1, const float* __restrict__ b1,
                     const float* __restrict__ w2, const float* __restrict__ b2,
                     float* __restrict__ ca){
    int b = blockIdx.x;
    int t = threadIdx.x;
    __shared__ float hid[CC/16];
    if (t < CC/16){
        float a = b1[t];
        for (int d = 0; d < CC; d++) a += w1[t*CC + d] * xc[b*CC + d];
        hid[t] = geluf(a);
    }
    __syncthreads();
    if (t < CC){
        float a = b2[t];
        #pragma unroll
        for (int i = 0; i < CC/16; i++) a += w2[t*(CC/16) + i] * hid[i];
        ca[b*CC + t] = sigmoidf(a);
    }
}

// ---------------- Kernel C: depthwise 9x9 conv + bias, scaled by ca ----------------
__global__ __launch_bounds__(256) void k_conv(const float* __restrict__ x, const float* __restrict__ w,
                       const float* __restrict__ bias, const float* __restrict__ ca,
                       float* __restrict__ x1){
    int gid = blockIdx.x * 256 + threadIdx.x; // B*C*L
    int l = gid & (LL-1); int bc = gid >> 12;
    int c = bc % CC; int b = bc / CC;
    int h = l >> 6, wq = l & 63;
    const float* xp = x + (size_t)bc * LL;
    const float* wp = w + c * 81;
    float acc = 0.f;
    #pragma unroll
    for (int ky = 0; ky < 9; ky++){
        int yy = h + ky - 4;
        if (yy < 0 || yy >= HH) continue;
        #pragma unroll
        for (int kx = 0; kx < 9; kx++){
            int xx = wq + kx - 4;
            if (xx < 0 || xx >= WW) continue;
            acc += xp[yy*WW + xx] * wp[ky*9 + kx];
        }
    }
    x1[gid] = (acc + bias[c]) * ca[b*CC + c];
}

// ---------------- Kernel D: rpe resize 7x7 -> 64x64 (b-independent) ----------------
__global__ __launch_bounds__(256) void k_rpe(const float* __restrict__ t, float* __restrict__ out){
    int gid = blockIdx.x * 256 + threadIdx.x; // C*L
    int l = gid & (LL-1); int c = gid >> 12;
    int h = l >> 6, w = l & 63;
    float sy = fmaxf((h + 0.5f) * (7.0f/64.0f) - 0.5f, 0.f);
    float sx = fmaxf((w + 0.5f) * (7.0f/64.0f) - 0.5f, 0.f);
    int y0 = (int)floorf(sy); int x0 = (int)floorf(sx);
    float wy = sy - (float)y0, wx = sx - (float)x0;
    int y1 = min(y0 + 1, 6), x1i = min(x0 + 1, 6);
    const float* tp = t + c * 49;
    float r0 = tp[y0*7 + x0] * (1.f - wy) + tp[y1*7 + x0] * wy;
    float r1 = tp[y0*7 + x1i] * (1.f - wy) + tp[y1*7 + x1i] * wy;
    out[gid] = r0 * (1.f - wx) + r1 * wx;
}

// ---------------- Kernel E: LayerNorm(C) + GELU + 1x1 conv, tiled ----------------
// Block = (b, 64-l tile), 256 thr = 4 waves; wave wg handles channels [24wg,24wg+24)
// with coalesced per-channel-row loads; v[24] kept in registers between the two
// passes; LDS reduces for (s,ss) and (a0,a1,a2).
__global__ __launch_bounds__(256) void k_off(const float* __restrict__ x1,
                      const float* __restrict__ g, const float* __restrict__ bta,
                      const float* __restrict__ w2,
                      float* __restrict__ posy, float* __restrict__ posx, float* __restrict__ path){
    int blk = blockIdx.x;            // b*64 + ltile
    int ltile = blk & 63; int b = blk >> 6;
    int lane = threadIdx.x & 63;
    int wg = threadIdx.x >> 6;       // 0..3
    int l = ltile * 64 + lane;
    const float* p = x1 + (size_t)b * CC * LL + l;
    float v[24];
    float s = 0.f, ss = 0.f;
    #pragma unroll
    for (int j = 0; j < 24; j++){
        float t = p[(size_t)(wg*24 + j) * LL];
        v[j] = t; s += t; ss += t*t;
    }
    __shared__ float ls[4][64], lss[4][64];
    ls[wg][lane] = s; lss[wg][lane] = ss;
    __syncthreads();
    s  = ls[0][lane]  + ls[1][lane]  + ls[2][lane]  + ls[3][lane];
    ss = lss[0][lane] + lss[1][lane] + lss[2][lane] + lss[3][lane];
    float m = s * (1.0f/CC);
    float rstd = rsqrtf(ss*(1.0f/CC) - m*m + 1e-5f);
    float a0 = 0.f, a1 = 0.f, a2 = 0.f;
    #pragma unroll
    for (int j = 0; j < 24; j++){
        int c = wg*24 + j;
        float xn = (v[j]-m)*rstd*g[c] + bta[c];
        float xg = geluf(xn);
        a0 = fmaf(w2[c],      xg, a0);
        a1 = fmaf(w2[CC+c],   xg, a1);
        a2 = fmaf(w2[2*CC+c], xg, a2);
    }
    __shared__ float la[3][4][64];
    la[0][wg][lane] = a0; la[1][wg][lane] = a1; la[2][wg][lane] = a2;
    __syncthreads();
    if (wg < 3){
        float a = la[wg][0][lane] + la[wg][1][lane] + la[wg][2][lane] + la[wg][3][lane];
        int h = l >> 6, w = l & 63;
        if (wg == 0)      posy[b*LL + l] = tanhf(a)*(1.0f/63.0f) + ((2*h+1)*(1.0f/63.0f) - 1.0f);
        else if (wg == 1) posx[b*LL + l] = tanhf(a)*(1.0f/63.0f) + ((2*w+1)*(1.0f/63.0f) - 1.0f);
        else              path[b*LL + l] = tanhf(a) + ((l + 0.5f)*(2.0f/4095.0f) - 1.0f);
    }
}

// ---------------- Kernel F: hybrid register/shuffle/LDS stable bitonic argsort ----------------
typedef unsigned long long u64s;
__device__ __forceinline__ u64s shflx64(u64s x, int m){
    int lo = __shfl_xor((int)(unsigned)x, m);
    int hi = __shfl_xor((int)(unsigned)(x >> 32), m);
    return ((u64s)(unsigned)hi << 32) | (unsigned)lo;
}
__device__ __forceinline__ void cex(u64s& a, u64s& b, bool up){
    u64s mn = a < b ? a : b;
    u64s mx = a < b ? b : a;
    a = up ? mn : mx;
    b = up ? mx : mn;
}
__global__ __launch_bounds__(1024) void k_sort(const float* __restrict__ path,
                                               int* __restrict__ idx, int* __restrict__ inv){
    int b = blockIdx.x;
    int t = threadIdx.x;
    __shared__ u64s lds[LL];
    u64s v[4];
    #pragma unroll
    for (int r = 0; r < 4; r++){
        int e = t*4 + r;
        unsigned u = __float_as_uint(path[b*LL + e]);
        u ^= (u >> 31) ? 0xFFFFFFFFu : 0x80000000u;   // monotonic float->uint
        v[r] = ((u64s)u << 32) | (unsigned)e;
    }
    for (int kk = 2; kk <= LL; kk <<= 1){
        for (int j = kk >> 1; j > 0; j >>= 1){
            if (j >= 256){
                __syncthreads();
                #pragma unroll
                for (int r = 0; r < 4; r++) lds[t*4 + r] = v[r];
                __syncthreads();
                #pragma unroll
                for (int r = 0; r < 4; r++){
                    int e = t*4 + r;
                    u64s pv = lds[e ^ j];
                    bool up    = ((e & kk) == 0);
                    bool lower = ((e & j) == 0);
                    u64s mn = v[r] < pv ? v[r] : pv;
                    u64s mx = v[r] < pv ? pv : v[r];
                    v[r] = (up == lower) ? mn : mx;
                }
            } else if (j >= 4){
                int m = j >> 2;
                #pragma unroll
                for (int r = 0; r < 4; r++){
                    u64s pv = shflx64(v[r], m);
                    bool up    = (((t*4 + r) & kk) == 0);
                    bool lower = ((t & m) == 0);
                    u64s mn = v[r] < pv ? v[r] : pv;
                    u64s mx = v[r] < pv ? pv : v[r];
                    v[r] = (up == lower) ? mn : mx;
                }
            } else if (j == 2){
                bool up = (((t*4) & kk) == 0);
                cex(v[0], v[2], up);
                cex(v[1], v[3], up);
            } else { // j == 1
                if (kk == 2){
                    cex(v[0], v[1], true);
                    cex(v[2], v[3], false);
                } else {
                    bool up = (((t*4) & kk) == 0);
                    cex(v[0], v[1], up);
                    cex(v[2], v[3], up);
                }
            }
        }
    }
    #pragma unroll
    for (int r = 0; r < 4; r++){
        int e = t*4 + r;
        int id = (int)(unsigned)(v[r] & 0xFFFFFFFFu);
        idx[b*LL + e] = id;
        inv[b*LL + id] = e;
    }
}

// ---------------- bilinear sample, zero padding ----------------
__device__ __forceinline__ float bilin0(const float* __restrict__ img, float gx, float gy){
    float fx = (gx + 1.f) * 31.5f;   // (W-1)/2 = 31.5
    float fy = (gy + 1.f) * 31.5f;
    float x0f = floorf(fx), y0f = floorf(fy);
    float wx = fx - x0f, wy = fy - y0f;
    int x0 = (int)x0f, y0 = (int)y0f;
    float acc = 0.f;
    bool vx0 = (x0 >= 0) & (x0 < WW), vx1 = (x0+1 >= 0) & (x0+1 < WW);
    bool vy0 = (y0 >= 0) & (y0 < HH), vy1 = (y0+1 >= 0) & (y0+1 < HH);
    if (vy0 & vx0) acc += img[y0*WW + x0]       * (1.f-wx) * (1.f-wy);
    if (vy0 & vx1) acc += img[y0*WW + x0+1]     * wx       * (1.f-wy);
    if (vy1 & vx0) acc += img[(y0+1)*WW + x0]   * (1.f-wx) * wy;
    if (vy1 & vx1) acc += img[(y0+1)*WW + x0+1] * wx       * wy;
    return acc;
}

// ---------------- Kernel S: x grid-sample + rpe grid-sample -> xd ----------------
__global__ __launch_bounds__(256) void k_sample(const float* __restrict__ x, const float* __restrict__ rpe,
                         const float* __restrict__ posy, const float* __restrict__ posx,
                         float* __restrict__ xd){
    int gid = blockIdx.x * 256 + threadIdx.x; // B*C*L
    int l = gid & (LL-1); int bc = gid >> 12;
    int b = bc / CC; int c = bc % CC;
    float gy = posy[b*LL + l], gx = posx[b*LL + l];
    float v = bilin0(x + (size_t)bc * LL, gx, gy);
    int h = l >> 6, w = l & 63;
    float ky = h * (128.0f/3969.0f) - 1.0f;  // linspace(0,64,64)/63*2-1
    float kx = w * (128.0f/3969.0f) - 1.0f;
    float v2 = bilin0(rpe + (size_t)c * LL, (kx - gx) * 0.5f, (ky - gy) * 0.5f);
    xd[gid] = v + v2;
}

// ---------------- Kernel G: projection, register-prefetch-96 (R6 known-good) ----------------
__global__ __launch_bounds__(64, 1) void k_proj(const float* __restrict__ x, const float* __restrict__ xd,
    const int* __restrict__ indices, const float* __restrict__ xpw, const float* __restrict__ dtw,
    const float* __restrict__ dtb, float* __restrict__ u2, float* __restrict__ dt,
    float* __restrict__ Bst, float* __restrict__ Cst){
    int blk = blockIdx.x;          // B*K*64 blocks
    int ltile = blk & 63; int bk = blk >> 6;
    int k = bk % KK; int b = bk / KK;
    const float* __restrict__ Wk = xpw + k*38*CC;   // uniform per block
    int l = ltile * 64 + threadIdx.x;
    int srcl = (k == 0) ? l : (k == 1 ? (LL-1-l) : indices[b*LL + l]);
    const float* xp = (k == 2 ? xd : x) + (size_t)b * CC * LL + srcl;

    // batch-load all 96 values: independent, all in flight
    float v[CC];
    #pragma unroll
    for (int d = 0; d < CC; d++) v[d] = xp[(size_t)d * LL];

    float acc[38];
    #pragma unroll
    for (int i = 0; i < 38; i++) acc[i] = 0.f;
    #pragma unroll
    for (int d = 0; d < CC; d++){
        #pragma unroll
        for (int i = 0; i < 38; i++) acc[i] += Wk[i*CC + d] * v[d];
    }

    size_t base = ((size_t)bk * LL + l) * NN;
    #pragma unroll
    for (int n = 0; n < NN; n++){
        Bst[base + n] = acc[RR + n];
        Cst[base + n] = acc[RR + NN + n];
    }
    if (k == 2){
        float* up = u2 + (size_t)b * CC * LL + l;
        #pragma unroll
        for (int d = 0; d < CC; d++) up[(size_t)d * LL] = v[d];
    }
    const float* __restrict__ Dw = dtw + k*CC*RR;
    const float* __restrict__ Db = dtb + k*CC;
    float* dtp = dt + (size_t)bk * CC * LL + l;
    #pragma unroll 8
    for (int d = 0; d < CC; d++){
        float sdt = Db[d];
        #pragma unroll
        for (int r = 0; r < RR; r++) sdt += acc[r] * Dw[d*RR + r];
        dtp[(size_t)d * LL] = softplusf(sdt);
    }
}

// ---------------- Kernel H: merged chunked-parallel selective scan ----------------
#define ST 32          // segments
#define TT 128         // steps per segment
template<int KIND>
__device__ __forceinline__ void scan_body(int b, int d, const float* __restrict__ usrc,
    const float* __restrict__ dt, const float* __restrict__ Bst, const float* __restrict__ Cst,
    const float* __restrict__ Alog, const float* __restrict__ Ds, float* __restrict__ ys,
    float* sA, float* sB, float* sCin){
    int bk = b * KK + KIND;
    int tid = threadIdx.x;
    int n = tid & 15; int s = tid >> 4;      // s in [0,32)
    int t0 = s * TT;

    float A  = -__expf(Alog[(KIND*CC + d)*NN + n]);
    float Dv = Ds[KIND*CC + d];

    const float* dtp = dt + ((size_t)bk * CC + d) * LL + t0;
    const float* ub = (KIND == 1)
        ? usrc + ((size_t)b*CC + d) * LL + (LL-4-t0)
        : usrc + ((size_t)b*CC + d) * LL + t0;
    const float* Bp = Bst + ((size_t)bk * LL + t0) * NN + n;
    const float* Cp = Cst + ((size_t)bk * LL + t0) * NN + n;
    float* yp = ys + ((size_t)bk * CC + d) * LL + t0;

    // Phase 1: local segment scan from h=0, track product of a
    float Aprod = 1.f, h = 0.f;
    for (int t = 0; t < TT; t += 4){
        float4 dq = *(const float4*)(dtp + t);
        float4 uq = (KIND == 1) ? *(const float4*)(ub - t) : *(const float4*)(ub + t);
        float u0, u1, u2v, u3;
        if (KIND == 1){ u0 = uq.w; u1 = uq.z; u2v = uq.y; u3 = uq.x; }
        else          { u0 = uq.x; u1 = uq.y; u2v = uq.z; u3 = uq.w; }
        float B0 = Bp[(t+0)*NN], B1 = Bp[(t+1)*NN], B2 = Bp[(t+2)*NN], B3 = Bp[(t+3)*NN];
        float a;
        a = __expf(dq.x * A); Aprod *= a; h = fmaf(a, h, dq.x * u0  * B0);
        a = __expf(dq.y * A); Aprod *= a; h = fmaf(a, h, dq.y * u1  * B1);
        a = __expf(dq.z * A); Aprod *= a; h = fmaf(a, h, dq.z * u2v * B2);
        a = __expf(dq.w * A); Aprod *= a; h = fmaf(a, h, dq.w * u3  * B3);
    }

    // Phase 2: exclusive scan of (Aprod, h) over segments, per chain n
    sA[s*16 + n] = Aprod;
    sB[s*16 + n] = h;
    __syncthreads();
    if (tid < 16){
        float c = 0.f;
        #pragma unroll
        for (int ss = 0; ss < ST; ss++){
            sCin[ss*16 + tid] = c;
            c = fmaf(sA[ss*16 + tid], c, sB[ss*16 + tid]);
        }
    }
    __syncthreads();
    float hc = sCin[s*16 + n];

    // Phase 3: replay with carry-in, emit y as float4
    for (int t = 0; t < TT; t += 4){
        float4 dq = *(const float4*)(dtp + t);
        float4 uq = (KIND == 1) ? *(const float4*)(ub - t) : *(const float4*)(ub + t);
        float u0, u1, u2v, u3;
        if (KIND == 1){ u0 = uq.w; u1 = uq.z; u2v = uq.y; u3 = uq.x; }
        else          { u0 = uq.x; u1 = uq.y; u2v = uq.z; u3 = uq.w; }
        float B0 = Bp[(t+0)*NN], B1 = Bp[(t+1)*NN], B2 = Bp[(t+2)*NN], B3 = Bp[(t+3)*NN];
        float C0 = Cp[(t+0)*NN], C1 = Cp[(t+1)*NN], C2 = Cp[(t+2)*NN], C3 = Cp[(t+3)*NN];
        float a, p;
        float4 yo;
        a = __expf(dq.x * A); hc = fmaf(a, hc, dq.x * u0  * B0); p = hc * C0;
        p += __shfl_xor(p,1); p += __shfl_xor(p,2); p += __shfl_xor(p,4); p += __shfl_xor(p,8);
        yo.x = fmaf(u0, Dv, p);
        a = __expf(dq.y * A); hc = fmaf(a, hc, dq.y * u1  * B1); p = hc * C1;
        p += __shfl_xor(p,1); p += __shfl_xor(p,2); p += __shfl_xor(p,4); p += __shfl_xor(p,8);
        yo.y = fmaf(u1, Dv, p);
        a = __expf(dq.z * A); hc = fmaf(a, hc, dq.z * u2v * B2); p = hc * C2;
        p += __shfl_xor(p,1); p += __shfl_xor(p,2); p += __shfl_xor(p,4); p += __shfl_xor(p,8);
        yo.z = fmaf(u2v, Dv, p);
        a = __expf(dq.w * A); hc = fmaf(a, hc, dq.w * u3  * B3); p = hc * C3;
        p += __shfl_xor(p,1); p += __shfl_xor(p,2); p += __shfl_xor(p,4); p += __shfl_xor(p,8);
        yo.w = fmaf(u3, Dv, p);
        if (n == 0) *(float4*)(yp + t) = yo;
    }
}

__global__ __launch_bounds__(512) void k_scan_all(const float* __restrict__ x, const float* __restrict__ u2,
    const float* __restrict__ dt, const float* __restrict__ Bst, const float* __restrict__ Cst,
    const float* __restrict__ Alog, const float* __restrict__ Ds, float* __restrict__ ys){
    __shared__ float sA[ST*16];
    __shared__ float sB[ST*16];
    __shared__ float sCin[ST*16];
    int blk = blockIdx.x;            // KK*BB*CC
    int k = blk / (BB*CC);
    int r = blk % (BB*CC);
    int d = r % CC; int b = r / CC;
    if (k == 0)      scan_body<0>(b, d, x,  dt, Bst, Cst, Alog, Ds, ys, sA, sB, sCin);
    else if (k == 1) scan_body<1>(b, d, x,  dt, Bst, Cst, Alog, Ds, ys, sA, sB, sCin);
    else             scan_body<2>(b, d, u2, dt, Bst, Cst, Alog, Ds, ys, sA, sB, sCin);
}

// ---------------- Kernel I: combine 3 paths + transpose to (B,L,C) ----------------
__global__ __launch_bounds__(256) void k_comb(const float* __restrict__ ys, const int* __restrict__ inv,
                                              float* __restrict__ out){
    int tile = blockIdx.x & 63; int b = blockIdx.x >> 6;
    int l0 = tile * 64;
    __shared__ float t0[CC * 65];
    __shared__ int invs[64];
    if (threadIdx.x < 64) invs[threadIdx.x] = inv[b*LL + l0 + threadIdx.x];
    __syncthreads();
    const float* y0p = ys + (size_t)(b*KK + 0) * CC * LL;
    const float* y1p = ys + (size_t)(b*KK + 1) * CC * LL;
    const float* y2p = ys + (size_t)(b*KK + 2) * CC * LL;
    for (int it = 0; it < 24; it++){
        int e = it * 256 + threadIdx.x;
        int li = e & 63; int c = e >> 6;
        int l = l0 + li;
        float v = y0p[(size_t)c*LL + l] + y1p[(size_t)c*LL + (LL-1-l)] + y2p[(size_t)c*LL + invs[li]];
        t0[c*65 + li] = v * (1.0f/3.0f);
    }
    __syncthreads();
    for (int it = 0; it < 24; it++){
        int e = it * 256 + threadIdx.x;
        int c = e % CC; int li = e / CC;
        out[((size_t)b*LL + l0 + li) * CC + c] = t0[c*65 + li];
    }
}

extern "C" void kernel_launch(void* const* d_in, const int* in_sizes, int n_in,
                              void* d_out, int out_size, void* d_ws, size_t ws_size,
                              hipStream_t stream){
    const float* x    = (const float*)d_in[0];
    const float* xpw  = (const float*)d_in[1];
    const float* dtw  = (const float*)d_in[2];
    const float* dtb  = (const float*)d_in[3];
    const float* Alog = (const float*)d_in[4];
    const float* Ds   = (const float*)d_in[5];
    const float* c1w  = (const float*)d_in[6];
    const float* c1b  = (const float*)d_in[7];
    const float* ca1w = (const float*)d_in[8];
    const float* ca1b = (const float*)d_in[9];
    const float* ca2w = (const float*)d_in[10];
    const float* ca2b = (const float*)d_in[11];
    const float* lng  = (const float*)d_in[12];
    const float* lnb  = (const float*)d_in[13];
    const float* c2w  = (const float*)d_in[14];
    const float* rpet = (const float*)d_in[15];
    float* out = (float*)d_out;

    float* ws   = (float*)d_ws;
    float* xc   = ws;                      // 384
    float* ca   = xc + 384;                // 384
    float* x1   = ca + 384;                // B*C*L = 1572864
    float* rpe  = x1 + (size_t)BB*CC*LL;   // C*L = 393216
    float* posy = rpe + (size_t)CC*LL;     // B*L
    float* posx = posy + (size_t)BB*LL;
    float* path = posx + (size_t)BB*LL;
    float* xd   = path + (size_t)BB*LL;    // B*C*L
    int*   idx  = (int*)(xd + (size_t)BB*CC*LL);   // B*L ints
    int*   inv  = idx + (size_t)BB*LL;             // B*L ints
    float* u2   = (float*)(inv + (size_t)BB*LL);   // B*C*L
    float* dtA  = u2 + (size_t)BB*CC*LL;           // B*K*C*L = 4718592
    float* Bst  = dtA + (size_t)BB*KK*CC*LL;       // B*K*L*N = 786432
    float* Cst  = Bst + (size_t)BB*KK*LL*NN;
    float* ysA  = Cst + (size_t)BB*KK*LL*NN;       // B*K*C*L

    k_mean  <<<BB*CC, 256, 0, stream>>>(x, xc);
    k_ca    <<<BB, 128, 0, stream>>>(xc, ca1w, ca1b, ca2w, ca2b, ca);
    k_conv  <<<(BB*CC*LL)/256, 256, 0, stream>>>(x, c1w, c1b, ca, x1);
    k_rpe   <<<(CC*LL)/256, 256, 0, stream>>>(rpet, rpe);
    k_off   <<<BB*64, 256, 0, stream>>>(x1, lng, lnb, c2w, posy, posx, path);
    k_sort  <<<BB, 1024, 0, stream>>>(path, idx, inv);
    k_sample<<<(BB*CC*LL)/256, 256, 0, stream>>>(x, rpe, posy, posx, xd);
    k_proj  <<<BB*KK*64, 64, 0, stream>>>(x, xd, idx, xpw, dtw, dtb, u2, dtA, Bst, Cst);
    k_scan_all<<<KK*BB*CC, 512, 0, stream>>>(x, u2, dtA, Bst, Cst, Alog, Ds, ysA);
    k_comb  <<<BB*64, 256, 0, stream>>>(ysA, inv, out);
}

// Round 9
// 356.566 us; speedup vs baseline: 1.5325x; 1.0249x over previous
//
#include <hip/hip_runtime.h>

#define BB 4
#define CC 96
#define HH 64
#define WW 64
#define LL 4096
#define KK 3
#define RR 6
#define NN 16

__device__ __forceinline__ float geluf(float x){
    return 0.5f * x * (1.0f + erff(x * 0.70710678118654752f));
}
__device__ __forceinline__ float softplusf(float x){
    return fmaxf(x, 0.0f) + log1pf(expf(-fabsf(x)));
}
__device__ __forceinline__ float sigmoidf(float x){
    return 1.0f / (1.0f + expf(-x));
}

// ---------------- Kernel A: per-(b,c) spatial mean ----------------
__global__ __launch_bounds__(256) void k_mean(const float* __restrict__ x, float* __restrict__ xc){
    int bc = blockIdx.x; // 0..B*C-1
    const float* p = x + (size_t)bc * LL;
    float s = 0.f;
    for (int i = threadIdx.x; i < LL; i += 256) s += p[i];
    __shared__ float red[256];
    red[threadIdx.x] = s; __syncthreads();
    for (int st = 128; st > 0; st >>= 1){
        if (threadIdx.x < st) red[threadIdx.x] += red[threadIdx.x + st];
        __syncthreads();
    }
    if (threadIdx.x == 0) xc[bc] = red[0] * (1.0f / LL);
}

// ---------------- Kernel B: channel-attention MLP ----------------
__global__ __launch_bounds__(128) void k_ca(const float* __restrict__ xc,
                     const float* __restrict__ w1, const float* __restrict__ b1,
                     const float* __restrict__ w2, const float* __restrict__ b2,
                     float* __restrict__ ca){
    int b = blockIdx.x;
    int t = threadIdx.x;
    __shared__ float hid[CC/16];
    if (t < CC/16){
        float a = b1[t];
        for (int d = 0; d < CC; d++) a += w1[t*CC + d] * xc[b*CC + d];
        hid[t] = geluf(a);
    }
    __syncthreads();
    if (t < CC){
        float a = b2[t];
        #pragma unroll
        for (int i = 0; i < CC/16; i++) a += w2[t*(CC/16) + i] * hid[i];
        ca[b*CC + t] = sigmoidf(a);
    }
}

// ---------------- Kernel C: depthwise 9x9 conv + bias, scaled by ca ----------------
__global__ __launch_bounds__(256) void k_conv(const float* __restrict__ x, const float* __restrict__ w,
                       const float* __restrict__ bias, const float* __restrict__ ca,
                       float* __restrict__ x1){
    int gid = blockIdx.x * 256 + threadIdx.x; // B*C*L
    int l = gid & (LL-1); int bc = gid >> 12;
    int c = bc % CC; int b = bc / CC;
    int h = l >> 6, wq = l & 63;
    const float* xp = x + (size_t)bc * LL;
    const float* wp = w + c * 81;
    float acc = 0.f;
    #pragma unroll
    for (int ky = 0; ky < 9; ky++){
        int yy = h + ky - 4;
        if (yy < 0 || yy >= HH) continue;
        #pragma unroll
        for (int kx = 0; kx < 9; kx++){
            int xx = wq + kx - 4;
            if (xx < 0 || xx >= WW) continue;
            acc += xp[yy*WW + xx] * wp[ky*9 + kx];
        }
    }
    x1[gid] = (acc + bias[c]) * ca[b*CC + c];
}

// ---------------- Kernel D: rpe resize 7x7 -> 64x64 (b-independent) ----------------
__global__ __launch_bounds__(256) void k_rpe(const float* __restrict__ t, float* __restrict__ out){
    int gid = blockIdx.x * 256 + threadIdx.x; // C*L
    int l = gid & (LL-1); int c = gid >> 12;
    int h = l >> 6, w = l & 63;
    float sy = fmaxf((h + 0.5f) * (7.0f/64.0f) - 0.5f, 0.f);
    float sx = fmaxf((w + 0.5f) * (7.0f/64.0f) - 0.5f, 0.f);
    int y0 = (int)floorf(sy); int x0 = (int)floorf(sx);
    float wy = sy - (float)y0, wx = sx - (float)x0;
    int y1 = min(y0 + 1, 6), x1i = min(x0 + 1, 6);
    const float* tp = t + c * 49;
    float r0 = tp[y0*7 + x0] * (1.f - wy) + tp[y1*7 + x0] * wy;
    float r1 = tp[y0*7 + x1i] * (1.f - wy) + tp[y1*7 + x1i] * wy;
    out[gid] = r0 * (1.f - wx) + r1 * wx;
}

// ---------------- Kernel E: LayerNorm(C) + GELU + 1x1 conv, tiled ----------------
__global__ __launch_bounds__(256) void k_off(const float* __restrict__ x1,
                      const float* __restrict__ g, const float* __restrict__ bta,
                      const float* __restrict__ w2,
                      float* __restrict__ posy, float* __restrict__ posx, float* __restrict__ path){
    int blk = blockIdx.x;            // b*64 + ltile
    int ltile = blk & 63; int b = blk >> 6;
    int lane = threadIdx.x & 63;
    int wg = threadIdx.x >> 6;       // 0..3
    int l = ltile * 64 + lane;
    const float* p = x1 + (size_t)b * CC * LL + l;
    float v[24];
    float s = 0.f, ss = 0.f;
    #pragma unroll
    for (int j = 0; j < 24; j++){
        float t = p[(size_t)(wg*24 + j) * LL];
        v[j] = t; s += t; ss += t*t;
    }
    __shared__ float ls[4][64], lss[4][64];
    ls[wg][lane] = s; lss[wg][lane] = ss;
    __syncthreads();
    s  = ls[0][lane]  + ls[1][lane]  + ls[2][lane]  + ls[3][lane];
    ss = lss[0][lane] + lss[1][lane] + lss[2][lane] + lss[3][lane];
    float m = s * (1.0f/CC);
    float rstd = rsqrtf(ss*(1.0f/CC) - m*m + 1e-5f);
    float a0 = 0.f, a1 = 0.f, a2 = 0.f;
    #pragma unroll
    for (int j = 0; j < 24; j++){
        int c = wg*24 + j;
        float xn = (v[j]-m)*rstd*g[c] + bta[c];
        float xg = geluf(xn);
        a0 = fmaf(w2[c],      xg, a0);
        a1 = fmaf(w2[CC+c],   xg, a1);
        a2 = fmaf(w2[2*CC+c], xg, a2);
    }
    __shared__ float la[3][4][64];
    la[0][wg][lane] = a0; la[1][wg][lane] = a1; la[2][wg][lane] = a2;
    __syncthreads();
    if (wg < 3){
        float a = la[wg][0][lane] + la[wg][1][lane] + la[wg][2][lane] + la[wg][3][lane];
        int h = l >> 6, w = l & 63;
        if (wg == 0)      posy[b*LL + l] = tanhf(a)*(1.0f/63.0f) + ((2*h+1)*(1.0f/63.0f) - 1.0f);
        else if (wg == 1) posx[b*LL + l] = tanhf(a)*(1.0f/63.0f) + ((2*w+1)*(1.0f/63.0f) - 1.0f);
        else              path[b*LL + l] = tanhf(a) + ((l + 0.5f)*(2.0f/4095.0f) - 1.0f);
    }
}

// ---------------- Kernel F: hybrid register/shuffle/LDS stable bitonic argsort ----------------
typedef unsigned long long u64s;
__device__ __forceinline__ u64s shflx64(u64s x, int m){
    int lo = __shfl_xor((int)(unsigned)x, m);
    int hi = __shfl_xor((int)(unsigned)(x >> 32), m);
    return ((u64s)(unsigned)hi << 32) | (unsigned)lo;
}
__device__ __forceinline__ void cex(u64s& a, u64s& b, bool up){
    u64s mn = a < b ? a : b;
    u64s mx = a < b ? b : a;
    a = up ? mn : mx;
    b = up ? mx : mn;
}
__global__ __launch_bounds__(1024) void k_sort(const float* __restrict__ path,
                                               int* __restrict__ idx, int* __restrict__ inv){
    int b = blockIdx.x;
    int t = threadIdx.x;
    __shared__ u64s lds[LL];
    u64s v[4];
    #pragma unroll
    for (int r = 0; r < 4; r++){
        int e = t*4 + r;
        unsigned u = __float_as_uint(path[b*LL + e]);
        u ^= (u >> 31) ? 0xFFFFFFFFu : 0x80000000u;   // monotonic float->uint
        v[r] = ((u64s)u << 32) | (unsigned)e;
    }
    for (int kk = 2; kk <= LL; kk <<= 1){
        for (int j = kk >> 1; j > 0; j >>= 1){
            if (j >= 256){
                __syncthreads();
                #pragma unroll
                for (int r = 0; r < 4; r++) lds[t*4 + r] = v[r];
                __syncthreads();
                #pragma unroll
                for (int r = 0; r < 4; r++){
                    int e = t*4 + r;
                    u64s pv = lds[e ^ j];
                    bool up    = ((e & kk) == 0);
                    bool lower = ((e & j) == 0);
                    u64s mn = v[r] < pv ? v[r] : pv;
                    u64s mx = v[r] < pv ? pv : v[r];
                    v[r] = (up == lower) ? mn : mx;
                }
            } else if (j >= 4){
                int m = j >> 2;
                #pragma unroll
                for (int r = 0; r < 4; r++){
                    u64s pv = shflx64(v[r], m);
                    bool up    = (((t*4 + r) & kk) == 0);
                    bool lower = ((t & m) == 0);
                    u64s mn = v[r] < pv ? v[r] : pv;
                    u64s mx = v[r] < pv ? pv : v[r];
                    v[r] = (up == lower) ? mn : mx;
                }
            } else if (j == 2){
                bool up = (((t*4) & kk) == 0);
                cex(v[0], v[2], up);
                cex(v[1], v[3], up);
            } else { // j == 1
                if (kk == 2){
                    cex(v[0], v[1], true);
                    cex(v[2], v[3], false);
                } else {
                    bool up = (((t*4) & kk) == 0);
                    cex(v[0], v[1], up);
                    cex(v[2], v[3], up);
                }
            }
        }
    }
    #pragma unroll
    for (int r = 0; r < 4; r++){
        int e = t*4 + r;
        int id = (int)(unsigned)(v[r] & 0xFFFFFFFFu);
        idx[b*LL + e] = id;
        inv[b*LL + id] = e;
    }
}

// ---------------- bilinear sample, zero padding ----------------
__device__ __forceinline__ float bilin0(const float* __restrict__ img, float gx, float gy){
    float fx = (gx + 1.f) * 31.5f;   // (W-1)/2 = 31.5
    float fy = (gy + 1.f) * 31.5f;
    float x0f = floorf(fx), y0f = floorf(fy);
    float wx = fx - x0f, wy = fy - y0f;
    int x0 = (int)x0f, y0 = (int)y0f;
    float acc = 0.f;
    bool vx0 = (x0 >= 0) & (x0 < WW), vx1 = (x0+1 >= 0) & (x0+1 < WW);
    bool vy0 = (y0 >= 0) & (y0 < HH), vy1 = (y0+1 >= 0) & (y0+1 < HH);
    if (vy0 & vx0) acc += img[y0*WW + x0]       * (1.f-wx) * (1.f-wy);
    if (vy0 & vx1) acc += img[y0*WW + x0+1]     * wx       * (1.f-wy);
    if (vy1 & vx0) acc += img[(y0+1)*WW + x0]   * (1.f-wx) * wy;
    if (vy1 & vx1) acc += img[(y0+1)*WW + x0+1] * wx       * wy;
    return acc;
}

// ---------------- Kernel S: x grid-sample + rpe grid-sample -> xd ----------------
__global__ __launch_bounds__(256) void k_sample(const float* __restrict__ x, const float* __restrict__ rpe,
                         const float* __restrict__ posy, const float* __restrict__ posx,
                         float* __restrict__ xd){
    int gid = blockIdx.x * 256 + threadIdx.x; // B*C*L
    int l = gid & (LL-1); int bc = gid >> 12;
    int b = bc / CC; int c = bc % CC;
    float gy = posy[b*LL + l], gx = posx[b*LL + l];
    float v = bilin0(x + (size_t)bc * LL, gx, gy);
    int h = l >> 6, w = l & 63;
    float ky = h * (128.0f/3969.0f) - 1.0f;  // linspace(0,64,64)/63*2-1
    float kx = w * (128.0f/3969.0f) - 1.0f;
    float v2 = bilin0(rpe + (size_t)c * LL, (kx - gx) * 0.5f, (ky - gy) * 0.5f);
    xd[gid] = v + v2;
}

// ---------------- Kernel G: projection, 3-wave output split (no LDS, no spill) ----------------
// Block = 192 thr = 3 waves, all on same 64 l's. Each wave loads v[96] (L1-hot
// after wave0) and computes a disjoint slice of the 38 output rows:
// wave0: rows 0..5 (dts) + dt softplus epilogue; wave1: rows 6..21 (B);
// wave2: rows 22..37 (C) + u2 store. No inter-wave communication.
__global__ __launch_bounds__(192, 1) void k_proj(const float* __restrict__ x, const float* __restrict__ xd,
    const int* __restrict__ indices, const float* __restrict__ xpw, const float* __restrict__ dtw,
    const float* __restrict__ dtb, float* __restrict__ u2, float* __restrict__ dt,
    float* __restrict__ Bst, float* __restrict__ Cst){
    int blk = blockIdx.x;          // B*K*64 blocks
    int ltile = blk & 63; int bk = blk >> 6;
    int k = bk % KK; int b = bk / KK;
    int lane = threadIdx.x & 63;
    int w = threadIdx.x >> 6;      // 0..2
    const float* __restrict__ Wk = xpw + k*38*CC;
    int l = ltile * 64 + lane;
    int srcl = (k == 0) ? l : (k == 1 ? (LL-1-l) : indices[b*LL + l]);
    const float* xp = (k == 2 ? xd : x) + (size_t)b * CC * LL + srcl;

    float v[CC];
    #pragma unroll
    for (int d = 0; d < CC; d++) v[d] = xp[(size_t)d * LL];

    if (w == 0){
        float acc[RR];
        #pragma unroll
        for (int i = 0; i < RR; i++) acc[i] = 0.f;
        #pragma unroll
        for (int d = 0; d < CC; d++){
            #pragma unroll
            for (int i = 0; i < RR; i++) acc[i] = fmaf(Wk[i*CC + d], v[d], acc[i]);
        }
        const float* __restrict__ Dw = dtw + k*CC*RR;
        const float* __restrict__ Db = dtb + k*CC;
        float* dtp = dt + (size_t)bk * CC * LL + l;
        #pragma unroll 8
        for (int d = 0; d < CC; d++){
            float sdt = Db[d];
            #pragma unroll
            for (int r = 0; r < RR; r++) sdt = fmaf(acc[r], Dw[d*RR + r], sdt);
            dtp[(size_t)d * LL] = softplusf(sdt);
        }
    } else if (w == 1){
        float acc[NN];
        #pragma unroll
        for (int i = 0; i < NN; i++) acc[i] = 0.f;
        #pragma unroll
        for (int d = 0; d < CC; d++){
            #pragma unroll
            for (int i = 0; i < NN; i++) acc[i] = fmaf(Wk[(RR + i)*CC + d], v[d], acc[i]);
        }
        size_t base = ((size_t)bk * LL + l) * NN;
        #pragma unroll
        for (int q = 0; q < 4; q++){
            float4 o; o.x = acc[q*4]; o.y = acc[q*4+1]; o.z = acc[q*4+2]; o.w = acc[q*4+3];
            *(float4*)(Bst + base + q*4) = o;
        }
    } else {
        float acc[NN];
        #pragma unroll
        for (int i = 0; i < NN; i++) acc[i] = 0.f;
        #pragma unroll
        for (int d = 0; d < CC; d++){
            #pragma unroll
            for (int i = 0; i < NN; i++) acc[i] = fmaf(Wk[(RR + NN + i)*CC + d], v[d], acc[i]);
        }
        size_t base = ((size_t)bk * LL + l) * NN;
        #pragma unroll
        for (int q = 0; q < 4; q++){
            float4 o; o.x = acc[q*4]; o.y = acc[q*4+1]; o.z = acc[q*4+2]; o.w = acc[q*4+3];
            *(float4*)(Cst + base + q*4) = o;
        }
        if (k == 2){
            float* up = u2 + (size_t)b * CC * LL + l;
            #pragma unroll
            for (int d = 0; d < CC; d++) up[(size_t)d * LL] = v[d];
        }
    }
}

// ---------------- Kernel H: merged selective scan, 4 n-chains per thread ----------------
// Block = one (bk,d), 512 thr = 128 segments x 4 n-groups; segment = 32 steps.
// Per thread: h[4], A[4]; B/C loaded as n-contiguous float4; dt/u as float4
// over t. y reduced over the 4 ng lanes with 2 quad-shuffles.
#define SEG 128        // segments
#define TL 32          // steps per segment
template<int KIND>
__device__ __forceinline__ void scan_body(int b, int d, const float* __restrict__ usrc,
    const float* __restrict__ dt, const float* __restrict__ Bst, const float* __restrict__ Cst,
    const float* __restrict__ Alog, const float* __restrict__ Ds, float* __restrict__ ys,
    float* sA, float* sB, float* sCin){
    int bk = b * KK + KIND;
    int tid = threadIdx.x;
    int ng = tid & 3;          // n = 4*ng + j
    int seg = tid >> 2;        // 0..127
    int t0 = seg * TL;

    const float4 A4 = *(const float4*)(Alog + (KIND*CC + d)*NN + 4*ng);
    float A[4] = { -__expf(A4.x), -__expf(A4.y), -__expf(A4.z), -__expf(A4.w) };
    float Dv = Ds[KIND*CC + d];

    const float* dtp = dt + ((size_t)bk * CC + d) * LL + t0;
    const float* ub = (KIND == 1)
        ? usrc + ((size_t)b*CC + d) * LL + (LL-4-t0)
        : usrc + ((size_t)b*CC + d) * LL + t0;
    const float* Bp = Bst + ((size_t)bk * LL + t0) * NN + 4*ng;
    const float* Cp = Cst + ((size_t)bk * LL + t0) * NN + 4*ng;
    float* yp = ys + ((size_t)bk * CC + d) * LL + t0;

    // Phase 1: local segment scan from h=0
    float Ap[4] = {1.f,1.f,1.f,1.f}, h[4] = {0.f,0.f,0.f,0.f};
    for (int t = 0; t < TL; t += 4){
        float4 dq = *(const float4*)(dtp + t);
        float4 uq = (KIND == 1) ? *(const float4*)(ub - t) : *(const float4*)(ub + t);
        float dd[4] = {dq.x, dq.y, dq.z, dq.w};
        float uu[4];
        if (KIND == 1){ uu[0]=uq.w; uu[1]=uq.z; uu[2]=uq.y; uu[3]=uq.x; }
        else          { uu[0]=uq.x; uu[1]=uq.y; uu[2]=uq.z; uu[3]=uq.w; }
        #pragma unroll
        for (int i = 0; i < 4; i++){
            float4 Bq = *(const float4*)(Bp + (t+i)*NN);
            float du = dd[i] * uu[i];
            float bb[4] = {Bq.x, Bq.y, Bq.z, Bq.w};
            #pragma unroll
            for (int j = 0; j < 4; j++){
                float a = __expf(dd[i] * A[j]);
                Ap[j] *= a;
                h[j] = fmaf(a, h[j], du * bb[j]);
            }
        }
    }

    // Phase 2: exclusive scan over 128 segments per chain n
    #pragma unroll
    for (int j = 0; j < 4; j++){
        sA[seg*16 + 4*ng + j] = Ap[j];
        sB[seg*16 + 4*ng + j] = h[j];
    }
    __syncthreads();
    if (tid < 16){
        float c = 0.f;
        for (int sg = 0; sg < SEG; sg++){
            sCin[sg*16 + tid] = c;
            c = fmaf(sA[sg*16 + tid], c, sB[sg*16 + tid]);
        }
    }
    __syncthreads();
    float hc[4];
    #pragma unroll
    for (int j = 0; j < 4; j++) hc[j] = sCin[seg*16 + 4*ng + j];

    // Phase 3: replay with carry-in, emit y float4 from ng==0 lanes
    for (int t = 0; t < TL; t += 4){
        float4 dq = *(const float4*)(dtp + t);
        float4 uq = (KIND == 1) ? *(const float4*)(ub - t) : *(const float4*)(ub + t);
        float dd[4] = {dq.x, dq.y, dq.z, dq.w};
        float uu[4];
        if (KIND == 1){ uu[0]=uq.w; uu[1]=uq.z; uu[2]=uq.y; uu[3]=uq.x; }
        else          { uu[0]=uq.x; uu[1]=uq.y; uu[2]=uq.z; uu[3]=uq.w; }
        float yo[4];
        #pragma unroll
        for (int i = 0; i < 4; i++){
            float4 Bq = *(const float4*)(Bp + (t+i)*NN);
            float4 Cq = *(const float4*)(Cp + (t+i)*NN);
            float du = dd[i] * uu[i];
            float bb[4] = {Bq.x, Bq.y, Bq.z, Bq.w};
            float cc[4] = {Cq.x, Cq.y, Cq.z, Cq.w};
            float p = 0.f;
            #pragma unroll
            for (int j = 0; j < 4; j++){
                float a = __expf(dd[i] * A[j]);
                hc[j] = fmaf(a, hc[j], du * bb[j]);
                p = fmaf(hc[j], cc[j], p);
            }
            p += __shfl_xor(p, 1);
            p += __shfl_xor(p, 2);
            yo[i] = fmaf(uu[i], Dv, p);
        }
        if (ng == 0){
            float4 o; o.x = yo[0]; o.y = yo[1]; o.z = yo[2]; o.w = yo[3];
            *(float4*)(yp + t) = o;
        }
    }
}

__global__ __launch_bounds__(512) void k_scan_all(const float* __restrict__ x, const float* __restrict__ u2,
    const float* __restrict__ dt, const float* __restrict__ Bst, const float* __restrict__ Cst,
    const float* __restrict__ Alog, const float* __restrict__ Ds, float* __restrict__ ys){
    __shared__ float sA[SEG*16];
    __shared__ float sB[SEG*16];
    __shared__ float sCin[SEG*16];
    int blk = blockIdx.x;            // KK*BB*CC
    int k = blk / (BB*CC);
    int r = blk % (BB*CC);
    int d = r % CC; int b = r / CC;
    if (k == 0)      scan_body<0>(b, d, x,  dt, Bst, Cst, Alog, Ds, ys, sA, sB, sCin);
    else if (k == 1) scan_body<1>(b, d, x,  dt, Bst, Cst, Alog, Ds, ys, sA, sB, sCin);
    else             scan_body<2>(b, d, u2, dt, Bst, Cst, Alog, Ds, ys, sA, sB, sCin);
}

// ---------------- Kernel I: combine 3 paths + transpose to (B,L,C) ----------------
__global__ __launch_bounds__(256) void k_comb(const float* __restrict__ ys, const int* __restrict__ inv,
                                              float* __restrict__ out){
    int tile = blockIdx.x & 63; int b = blockIdx.x >> 6;
    int l0 = tile * 64;
    __shared__ float t0[CC * 65];
    __shared__ int invs[64];
    if (threadIdx.x < 64) invs[threadIdx.x] = inv[b*LL + l0 + threadIdx.x];
    __syncthreads();
    const float* y0p = ys + (size_t)(b*KK + 0) * CC * LL;
    const float* y1p = ys + (size_t)(b*KK + 1) * CC * LL;
    const float* y2p = ys + (size_t)(b*KK + 2) * CC * LL;
    for (int it = 0; it < 24; it++){
        int e = it * 256 + threadIdx.x;
        int li = e & 63; int c = e >> 6;
        int l = l0 + li;
        float v = y0p[(size_t)c*LL + l] + y1p[(size_t)c*LL + (LL-1-l)] + y2p[(size_t)c*LL + invs[li]];
        t0[c*65 + li] = v * (1.0f/3.0f);
    }
    __syncthreads();
    for (int it = 0; it < 24; it++){
        int e = it * 256 + threadIdx.x;
        int c = e % CC; int li = e / CC;
        out[((size_t)b*LL + l0 + li) * CC + c] = t0[c*65 + li];
    }
}

extern "C" void kernel_launch(void* const* d_in, const int* in_sizes, int n_in,
                              void* d_out, int out_size, void* d_ws, size_t ws_size,
                              hipStream_t stream){
    const float* x    = (const float*)d_in[0];
    const float* xpw  = (const float*)d_in[1];
    const float* dtw  = (const float*)d_in[2];
    const float* dtb  = (const float*)d_in[3];
    const float* Alog = (const float*)d_in[4];
    const float* Ds   = (const float*)d_in[5];
    const float* c1w  = (const float*)d_in[6];
    const float* c1b  = (const float*)d_in[7];
    const float* ca1w = (const float*)d_in[8];
    const float* ca1b = (const float*)d_in[9];
    const float* ca2w = (const float*)d_in[10];
    const float* ca2b = (const float*)d_in[11];
    const float* lng  = (const float*)d_in[12];
    const float* lnb  = (const float*)d_in[13];
    const float* c2w  = (const float*)d_in[14];
    const float* rpet = (const float*)d_in[15];
    float* out = (float*)d_out;

    float* ws   = (float*)d_ws;
    float* xc   = ws;                      // 384
    float* ca   = xc + 384;                // 384
    float* x1   = ca + 384;                // B*C*L = 1572864
    float* rpe  = x1 + (size_t)BB*CC*LL;   // C*L = 393216
    float* posy = rpe + (size_t)CC*LL;     // B*L
    float* posx = posy + (size_t)BB*LL;
    float* path = posx + (size_t)BB*LL;
    float* xd   = path + (size_t)BB*LL;    // B*C*L
    int*   idx  = (int*)(xd + (size_t)BB*CC*LL);   // B*L ints
    int*   inv  = idx + (size_t)BB*LL;             // B*L ints
    float* u2   = (float*)(inv + (size_t)BB*LL);   // B*C*L
    float* dtA  = u2 + (size_t)BB*CC*LL;           // B*K*C*L = 4718592
    float* Bst  = dtA + (size_t)BB*KK*CC*LL;       // B*K*L*N = 786432
    float* Cst  = Bst + (size_t)BB*KK*LL*NN;
    float* ysA  = Cst + (size_t)BB*KK*LL*NN;       // B*K*C*L

    k_mean  <<<BB*CC, 256, 0, stream>>>(x, xc);
    k_ca    <<<BB, 128, 0, stream>>>(xc, ca1w, ca1b, ca2w, ca2b, ca);
    k_conv  <<<(BB*CC*LL)/256, 256, 0, stream>>>(x, c1w, c1b, ca, x1);
    k_rpe   <<<(CC*LL)/256, 256, 0, stream>>>(rpet, rpe);
    k_off   <<<BB*64, 256, 0, stream>>>(x1, lng, lnb, c2w, posy, posx, path);
    k_sort  <<<BB, 1024, 0, stream>>>(path, idx, inv);
    k_sample<<<(BB*CC*LL)/256, 256, 0, stream>>>(x, rpe, posy, posx, xd);
    k_proj  <<<BB*KK*64, 192, 0, stream>>>(x, xd, idx, xpw, dtw, dtb, u2, dtA, Bst, Cst);
    k_scan_all<<<KK*BB*CC, 512, 0, stream>>>(x, u2, dtA, Bst, Cst, Alog, Ds, ysA);
    k_comb  <<<BB*64, 256, 0, stream>>>(ysA, inv, out);
}

// Round 10
// 351.516 us; speedup vs baseline: 1.5545x; 1.0144x over previous
//
#include <hip/hip_runtime.h>

#define BB 4
#define CC 96
#define HH 64
#define WW 64
#define LL 4096
#define KK 3
#define RR 6
#define NN 16

__device__ __forceinline__ float geluf(float x){
    return 0.5f * x * (1.0f + erff(x * 0.70710678118654752f));
}
__device__ __forceinline__ float softplusf(float x){
    return fmaxf(x, 0.0f) + log1pf(expf(-fabsf(x)));
}
__device__ __forceinline__ float sigmoidf(float x){
    return 1.0f / (1.0f + expf(-x));
}

// ---------------- Kernel A: per-(b,c) spatial mean ----------------
__global__ __launch_bounds__(256) void k_mean(const float* __restrict__ x, float* __restrict__ xc){
    int bc = blockIdx.x; // 0..B*C-1
    const float* p = x + (size_t)bc * LL;
    float s = 0.f;
    for (int i = threadIdx.x; i < LL; i += 256) s += p[i];
    __shared__ float red[256];
    red[threadIdx.x] = s; __syncthreads();
    for (int st = 128; st > 0; st >>= 1){
        if (threadIdx.x < st) red[threadIdx.x] += red[threadIdx.x + st];
        __syncthreads();
    }
    if (threadIdx.x == 0) xc[bc] = red[0] * (1.0f / LL);
}

// ---------------- Kernel B: channel-attention MLP ----------------
__global__ __launch_bounds__(128) void k_ca(const float* __restrict__ xc,
                     const float* __restrict__ w1, const float* __restrict__ b1,
                     const float* __restrict__ w2, const float* __restrict__ b2,
                     float* __restrict__ ca){
    int b = blockIdx.x;
    int t = threadIdx.x;
    __shared__ float hid[CC/16];
    if (t < CC/16){
        float a = b1[t];
        for (int d = 0; d < CC; d++) a += w1[t*CC + d] * xc[b*CC + d];
        hid[t] = geluf(a);
    }
    __syncthreads();
    if (t < CC){
        float a = b2[t];
        #pragma unroll
        for (int i = 0; i < CC/16; i++) a += w2[t*(CC/16) + i] * hid[i];
        ca[b*CC + t] = sigmoidf(a);
    }
}

// ---------------- Kernel C: depthwise 9x9 conv + bias, scaled by ca ----------------
__global__ __launch_bounds__(256) void k_conv(const float* __restrict__ x, const float* __restrict__ w,
                       const float* __restrict__ bias, const float* __restrict__ ca,
                       float* __restrict__ x1){
    int gid = blockIdx.x * 256 + threadIdx.x; // B*C*L
    int l = gid & (LL-1); int bc = gid >> 12;
    int c = bc % CC; int b = bc / CC;
    int h = l >> 6, wq = l & 63;
    const float* xp = x + (size_t)bc * LL;
    const float* wp = w + c * 81;
    float acc = 0.f;
    #pragma unroll
    for (int ky = 0; ky < 9; ky++){
        int yy = h + ky - 4;
        if (yy < 0 || yy >= HH) continue;
        #pragma unroll
        for (int kx = 0; kx < 9; kx++){
            int xx = wq + kx - 4;
            if (xx < 0 || xx >= WW) continue;
            acc += xp[yy*WW + xx] * wp[ky*9 + kx];
        }
    }
    x1[gid] = (acc + bias[c]) * ca[b*CC + c];
}

// ---------------- Kernel D: rpe resize 7x7 -> 64x64 (b-independent) ----------------
__global__ __launch_bounds__(256) void k_rpe(const float* __restrict__ t, float* __restrict__ out){
    int gid = blockIdx.x * 256 + threadIdx.x; // C*L
    int l = gid & (LL-1); int c = gid >> 12;
    int h = l >> 6, w = l & 63;
    float sy = fmaxf((h + 0.5f) * (7.0f/64.0f) - 0.5f, 0.f);
    float sx = fmaxf((w + 0.5f) * (7.0f/64.0f) - 0.5f, 0.f);
    int y0 = (int)floorf(sy); int x0 = (int)floorf(sx);
    float wy = sy - (float)y0, wx = sx - (float)x0;
    int y1 = min(y0 + 1, 6), x1i = min(x0 + 1, 6);
    const float* tp = t + c * 49;
    float r0 = tp[y0*7 + x0] * (1.f - wy) + tp[y1*7 + x0] * wy;
    float r1 = tp[y0*7 + x1i] * (1.f - wy) + tp[y1*7 + x1i] * wy;
    out[gid] = r0 * (1.f - wx) + r1 * wx;
}

// ---------------- Kernel E: LayerNorm(C) + GELU + 1x1 conv, tiled ----------------
__global__ __launch_bounds__(256) void k_off(const float* __restrict__ x1,
                      const float* __restrict__ g, const float* __restrict__ bta,
                      const float* __restrict__ w2,
                      float* __restrict__ posy, float* __restrict__ posx, float* __restrict__ path){
    int blk = blockIdx.x;            // b*64 + ltile
    int ltile = blk & 63; int b = blk >> 6;
    int lane = threadIdx.x & 63;
    int wg = threadIdx.x >> 6;       // 0..3
    int l = ltile * 64 + lane;
    const float* p = x1 + (size_t)b * CC * LL + l;
    float v[24];
    float s = 0.f, ss = 0.f;
    #pragma unroll
    for (int j = 0; j < 24; j++){
        float t = p[(size_t)(wg*24 + j) * LL];
        v[j] = t; s += t; ss += t*t;
    }
    __shared__ float ls[4][64], lss[4][64];
    ls[wg][lane] = s; lss[wg][lane] = ss;
    __syncthreads();
    s  = ls[0][lane]  + ls[1][lane]  + ls[2][lane]  + ls[3][lane];
    ss = lss[0][lane] + lss[1][lane] + lss[2][lane] + lss[3][lane];
    float m = s * (1.0f/CC);
    float rstd = rsqrtf(ss*(1.0f/CC) - m*m + 1e-5f);
    float a0 = 0.f, a1 = 0.f, a2 = 0.f;
    #pragma unroll
    for (int j = 0; j < 24; j++){
        int c = wg*24 + j;
        float xn = (v[j]-m)*rstd*g[c] + bta[c];
        float xg = geluf(xn);
        a0 = fmaf(w2[c],      xg, a0);
        a1 = fmaf(w2[CC+c],   xg, a1);
        a2 = fmaf(w2[2*CC+c], xg, a2);
    }
    __shared__ float la[3][4][64];
    la[0][wg][lane] = a0; la[1][wg][lane] = a1; la[2][wg][lane] = a2;
    __syncthreads();
    if (wg < 3){
        float a = la[wg][0][lane] + la[wg][1][lane] + la[wg][2][lane] + la[wg][3][lane];
        int h = l >> 6, w = l & 63;
        if (wg == 0)      posy[b*LL + l] = tanhf(a)*(1.0f/63.0f) + ((2*h+1)*(1.0f/63.0f) - 1.0f);
        else if (wg == 1) posx[b*LL + l] = tanhf(a)*(1.0f/63.0f) + ((2*w+1)*(1.0f/63.0f) - 1.0f);
        else              path[b*LL + l] = tanhf(a) + ((l + 0.5f)*(2.0f/4095.0f) - 1.0f);
    }
}

// ---------------- Kernel F: hybrid register/shuffle/LDS stable bitonic argsort ----------------
typedef unsigned long long u64s;
__device__ __forceinline__ u64s shflx64(u64s x, int m){
    int lo = __shfl_xor((int)(unsigned)x, m);
    int hi = __shfl_xor((int)(unsigned)(x >> 32), m);
    return ((u64s)(unsigned)hi << 32) | (unsigned)lo;
}
__device__ __forceinline__ void cex(u64s& a, u64s& b, bool up){
    u64s mn = a < b ? a : b;
    u64s mx = a < b ? b : a;
    a = up ? mn : mx;
    b = up ? mx : mn;
}
__global__ __launch_bounds__(1024) void k_sort(const float* __restrict__ path,
                                               int* __restrict__ idx, int* __restrict__ inv){
    int b = blockIdx.x;
    int t = threadIdx.x;
    __shared__ u64s lds[LL];
    u64s v[4];
    #pragma unroll
    for (int r = 0; r < 4; r++){
        int e = t*4 + r;
        unsigned u = __float_as_uint(path[b*LL + e]);
        u ^= (u >> 31) ? 0xFFFFFFFFu : 0x80000000u;   // monotonic float->uint
        v[r] = ((u64s)u << 32) | (unsigned)e;
    }
    for (int kk = 2; kk <= LL; kk <<= 1){
        for (int j = kk >> 1; j > 0; j >>= 1){
            if (j >= 256){
                __syncthreads();
                #pragma unroll
                for (int r = 0; r < 4; r++) lds[t*4 + r] = v[r];
                __syncthreads();
                #pragma unroll
                for (int r = 0; r < 4; r++){
                    int e = t*4 + r;
                    u64s pv = lds[e ^ j];
                    bool up    = ((e & kk) == 0);
                    bool lower = ((e & j) == 0);
                    u64s mn = v[r] < pv ? v[r] : pv;
                    u64s mx = v[r] < pv ? pv : v[r];
                    v[r] = (up == lower) ? mn : mx;
                }
            } else if (j >= 4){
                int m = j >> 2;
                #pragma unroll
                for (int r = 0; r < 4; r++){
                    u64s pv = shflx64(v[r], m);
                    bool up    = (((t*4 + r) & kk) == 0);
                    bool lower = ((t & m) == 0);
                    u64s mn = v[r] < pv ? v[r] : pv;
                    u64s mx = v[r] < pv ? pv : v[r];
                    v[r] = (up == lower) ? mn : mx;
                }
            } else if (j == 2){
                bool up = (((t*4) & kk) == 0);
                cex(v[0], v[2], up);
                cex(v[1], v[3], up);
            } else { // j == 1
                if (kk == 2){
                    cex(v[0], v[1], true);
                    cex(v[2], v[3], false);
                } else {
                    bool up = (((t*4) & kk) == 0);
                    cex(v[0], v[1], up);
                    cex(v[2], v[3], up);
                }
            }
        }
    }
    #pragma unroll
    for (int r = 0; r < 4; r++){
        int e = t*4 + r;
        int id = (int)(unsigned)(v[r] & 0xFFFFFFFFu);
        idx[b*LL + e] = id;
        inv[b*LL + id] = e;
    }
}

// ---------------- bilinear sample, zero padding ----------------
__device__ __forceinline__ float bilin0(const float* __restrict__ img, float gx, float gy){
    float fx = (gx + 1.f) * 31.5f;   // (W-1)/2 = 31.5
    float fy = (gy + 1.f) * 31.5f;
    float x0f = floorf(fx), y0f = floorf(fy);
    float wx = fx - x0f, wy = fy - y0f;
    int x0 = (int)x0f, y0 = (int)y0f;
    float acc = 0.f;
    bool vx0 = (x0 >= 0) & (x0 < WW), vx1 = (x0+1 >= 0) & (x0+1 < WW);
    bool vy0 = (y0 >= 0) & (y0 < HH), vy1 = (y0+1 >= 0) & (y0+1 < HH);
    if (vy0 & vx0) acc += img[y0*WW + x0]       * (1.f-wx) * (1.f-wy);
    if (vy0 & vx1) acc += img[y0*WW + x0+1]     * wx       * (1.f-wy);
    if (vy1 & vx0) acc += img[(y0+1)*WW + x0]   * (1.f-wx) * wy;
    if (vy1 & vx1) acc += img[(y0+1)*WW + x0+1] * wx       * wy;
    return acc;
}

// ---------------- Kernel S: x grid-sample + rpe grid-sample -> xd ----------------
__global__ __launch_bounds__(256) void k_sample(const float* __restrict__ x, const float* __restrict__ rpe,
                         const float* __restrict__ posy, const float* __restrict__ posx,
                         float* __restrict__ xd){
    int gid = blockIdx.x * 256 + threadIdx.x; // B*C*L
    int l = gid & (LL-1); int bc = gid >> 12;
    int b = bc / CC; int c = bc % CC;
    float gy = posy[b*LL + l], gx = posx[b*LL + l];
    float v = bilin0(x + (size_t)bc * LL, gx, gy);
    int h = l >> 6, w = l & 63;
    float ky = h * (128.0f/3969.0f) - 1.0f;  // linspace(0,64,64)/63*2-1
    float kx = w * (128.0f/3969.0f) - 1.0f;
    float v2 = bilin0(rpe + (size_t)c * LL, (kx - gx) * 0.5f, (ky - gy) * 0.5f);
    xd[gid] = v + v2;
}

// ---------------- Kernel G: projection, 3-wave output split + shared v in LDS ----------------
// Block = 192 thr = 3 waves on the same 64 l's. Cooperative load: wave w loads
// channels [32w,32w+32) into vsh (one global pass instead of three). Then
// wave0: dt rows+epilogue; wave1: B rows; wave2: C rows + u2 store.
__global__ __launch_bounds__(192, 1) void k_proj(const float* __restrict__ x, const float* __restrict__ xd,
    const int* __restrict__ indices, const float* __restrict__ xpw, const float* __restrict__ dtw,
    const float* __restrict__ dtb, float* __restrict__ u2, float* __restrict__ dt,
    float* __restrict__ Bst, float* __restrict__ Cst){
    int blk = blockIdx.x;          // B*K*64 blocks
    int ltile = blk & 63; int bk = blk >> 6;
    int k = bk % KK; int b = bk / KK;
    int lane = threadIdx.x & 63;
    int w = threadIdx.x >> 6;      // 0..2
    const float* __restrict__ Wk = xpw + k*38*CC;
    int l = ltile * 64 + lane;
    int srcl = (k == 0) ? l : (k == 1 ? (LL-1-l) : indices[b*LL + l]);
    const float* xp = (k == 2 ? xd : x) + (size_t)b * CC * LL + srcl;

    __shared__ float vsh[CC*64];   // 24 KB
    #pragma unroll
    for (int j = 0; j < 32; j++){
        int d = w*32 + j;
        vsh[d*64 + lane] = xp[(size_t)d * LL];
    }
    __syncthreads();

    if (w == 0){
        float acc[RR];
        #pragma unroll
        for (int i = 0; i < RR; i++) acc[i] = 0.f;
        for (int d = 0; d < CC; d++){
            float vv = vsh[d*64 + lane];
            #pragma unroll
            for (int i = 0; i < RR; i++) acc[i] = fmaf(Wk[i*CC + d], vv, acc[i]);
        }
        const float* __restrict__ Dw = dtw + k*CC*RR;
        const float* __restrict__ Db = dtb + k*CC;
        float* dtp = dt + (size_t)bk * CC * LL + l;
        #pragma unroll 8
        for (int d = 0; d < CC; d++){
            float sdt = Db[d];
            #pragma unroll
            for (int r = 0; r < RR; r++) sdt = fmaf(acc[r], Dw[d*RR + r], sdt);
            dtp[(size_t)d * LL] = softplusf(sdt);
        }
    } else if (w == 1){
        float acc[NN];
        #pragma unroll
        for (int i = 0; i < NN; i++) acc[i] = 0.f;
        for (int d = 0; d < CC; d++){
            float vv = vsh[d*64 + lane];
            #pragma unroll
            for (int i = 0; i < NN; i++) acc[i] = fmaf(Wk[(RR + i)*CC + d], vv, acc[i]);
        }
        size_t base = ((size_t)bk * LL + l) * NN;
        #pragma unroll
        for (int q = 0; q < 4; q++){
            float4 o; o.x = acc[q*4]; o.y = acc[q*4+1]; o.z = acc[q*4+2]; o.w = acc[q*4+3];
            *(float4*)(Bst + base + q*4) = o;
        }
    } else {
        float acc[NN];
        #pragma unroll
        for (int i = 0; i < NN; i++) acc[i] = 0.f;
        for (int d = 0; d < CC; d++){
            float vv = vsh[d*64 + lane];
            #pragma unroll
            for (int i = 0; i < NN; i++) acc[i] = fmaf(Wk[(RR + NN + i)*CC + d], vv, acc[i]);
        }
        size_t base = ((size_t)bk * LL + l) * NN;
        #pragma unroll
        for (int q = 0; q < 4; q++){
            float4 o; o.x = acc[q*4]; o.y = acc[q*4+1]; o.z = acc[q*4+2]; o.w = acc[q*4+3];
            *(float4*)(Cst + base + q*4) = o;
        }
        if (k == 2){
            float* up = u2 + (size_t)b * CC * LL + l;
            #pragma unroll 8
            for (int d = 0; d < CC; d++) up[(size_t)d * LL] = vsh[d*64 + lane];
        }
    }
}

// ---------------- Kernel H: merged selective scan, 4 n-chains/thread, LDS dt/u cache ----------------
// Block = one (bk,d), 512 thr = 128 segments x 4 n-groups; segment = 32 steps.
// Phase 1 stages scan-ordered dt/u into LDS (ng==0 lanes); phase 3 reads LDS
// (ds_read_b128, broadcast across ng) -> no global re-fetch of dt/u.
#define SEG 128        // segments
#define TL 32          // steps per segment
template<int KIND>
__device__ __forceinline__ void scan_body(int b, int d, const float* __restrict__ usrc,
    const float* __restrict__ dt, const float* __restrict__ Bst, const float* __restrict__ Cst,
    const float* __restrict__ Alog, const float* __restrict__ Ds, float* __restrict__ ys,
    float* sA, float* sB, float* sCin, float* sdt, float* su){
    int bk = b * KK + KIND;
    int tid = threadIdx.x;
    int ng = tid & 3;          // n = 4*ng + j
    int seg = tid >> 2;        // 0..127
    int t0 = seg * TL;

    const float4 A4 = *(const float4*)(Alog + (KIND*CC + d)*NN + 4*ng);
    float A[4] = { -__expf(A4.x), -__expf(A4.y), -__expf(A4.z), -__expf(A4.w) };
    float Dv = Ds[KIND*CC + d];

    const float* dtp = dt + ((size_t)bk * CC + d) * LL + t0;
    const float* ub = (KIND == 1)
        ? usrc + ((size_t)b*CC + d) * LL + (LL-4-t0)
        : usrc + ((size_t)b*CC + d) * LL + t0;
    const float* Bp = Bst + ((size_t)bk * LL + t0) * NN + 4*ng;
    const float* Cp = Cst + ((size_t)bk * LL + t0) * NN + 4*ng;
    float* yp = ys + ((size_t)bk * CC + d) * LL + t0;

    // Phase 1: local segment scan from h=0; stage dt/u (scan order) into LDS
    float Ap[4] = {1.f,1.f,1.f,1.f}, h[4] = {0.f,0.f,0.f,0.f};
    for (int t = 0; t < TL; t += 4){
        float4 dq = *(const float4*)(dtp + t);
        float4 uq = (KIND == 1) ? *(const float4*)(ub - t) : *(const float4*)(ub + t);
        float dd[4] = {dq.x, dq.y, dq.z, dq.w};
        float uu[4];
        if (KIND == 1){ uu[0]=uq.w; uu[1]=uq.z; uu[2]=uq.y; uu[3]=uq.x; }
        else          { uu[0]=uq.x; uu[1]=uq.y; uu[2]=uq.z; uu[3]=uq.w; }
        if (ng == 0){
            *(float4*)(sdt + t0 + t) = dq;
            float4 us; us.x = uu[0]; us.y = uu[1]; us.z = uu[2]; us.w = uu[3];
            *(float4*)(su + t0 + t) = us;
        }
        #pragma unroll
        for (int i = 0; i < 4; i++){
            float4 Bq = *(const float4*)(Bp + (t+i)*NN);
            float du = dd[i] * uu[i];
            float bb[4] = {Bq.x, Bq.y, Bq.z, Bq.w};
            #pragma unroll
            for (int j = 0; j < 4; j++){
                float a = __expf(dd[i] * A[j]);
                Ap[j] *= a;
                h[j] = fmaf(a, h[j], du * bb[j]);
            }
        }
    }

    // Phase 2: exclusive scan over 128 segments per chain n
    #pragma unroll
    for (int j = 0; j < 4; j++){
        sA[seg*16 + 4*ng + j] = Ap[j];
        sB[seg*16 + 4*ng + j] = h[j];
    }
    __syncthreads();
    if (tid < 16){
        float c = 0.f;
        for (int sg = 0; sg < SEG; sg++){
            sCin[sg*16 + tid] = c;
            c = fmaf(sA[sg*16 + tid], c, sB[sg*16 + tid]);
        }
    }
    __syncthreads();
    float hc[4];
    #pragma unroll
    for (int j = 0; j < 4; j++) hc[j] = sCin[seg*16 + 4*ng + j];

    // Phase 3: replay with carry-in from LDS dt/u, emit y float4 from ng==0 lanes
    for (int t = 0; t < TL; t += 4){
        float4 dq = *(const float4*)(sdt + t0 + t);
        float4 us = *(const float4*)(su + t0 + t);
        float dd[4] = {dq.x, dq.y, dq.z, dq.w};
        float uu[4] = {us.x, us.y, us.z, us.w};
        float yo[4];
        #pragma unroll
        for (int i = 0; i < 4; i++){
            float4 Bq = *(const float4*)(Bp + (t+i)*NN);
            float4 Cq = *(const float4*)(Cp + (t+i)*NN);
            float du = dd[i] * uu[i];
            float bb[4] = {Bq.x, Bq.y, Bq.z, Bq.w};
            float cc[4] = {Cq.x, Cq.y, Cq.z, Cq.w};
            float p = 0.f;
            #pragma unroll
            for (int j = 0; j < 4; j++){
                float a = __expf(dd[i] * A[j]);
                hc[j] = fmaf(a, hc[j], du * bb[j]);
                p = fmaf(hc[j], cc[j], p);
            }
            p += __shfl_xor(p, 1);
            p += __shfl_xor(p, 2);
            yo[i] = fmaf(uu[i], Dv, p);
        }
        if (ng == 0){
            float4 o; o.x = yo[0]; o.y = yo[1]; o.z = yo[2]; o.w = yo[3];
            *(float4*)(yp + t) = o;
        }
    }
}

__global__ __launch_bounds__(512) void k_scan_all(const float* __restrict__ x, const float* __restrict__ u2,
    const float* __restrict__ dt, const float* __restrict__ Bst, const float* __restrict__ Cst,
    const float* __restrict__ Alog, const float* __restrict__ Ds, float* __restrict__ ys){
    __shared__ float sA[SEG*16];
    __shared__ float sB[SEG*16];
    __shared__ float sCin[SEG*16];
    __shared__ float sdt[LL];
    __shared__ float su[LL];
    int blk = blockIdx.x;            // KK*BB*CC
    int k = blk / (BB*CC);
    int r = blk % (BB*CC);
    int d = r % CC; int b = r / CC;
    if (k == 0)      scan_body<0>(b, d, x,  dt, Bst, Cst, Alog, Ds, ys, sA, sB, sCin, sdt, su);
    else if (k == 1) scan_body<1>(b, d, x,  dt, Bst, Cst, Alog, Ds, ys, sA, sB, sCin, sdt, su);
    else             scan_body<2>(b, d, u2, dt, Bst, Cst, Alog, Ds, ys, sA, sB, sCin, sdt, su);
}

// ---------------- Kernel I: combine 3 paths + transpose to (B,L,C) ----------------
__global__ __launch_bounds__(256) void k_comb(const float* __restrict__ ys, const int* __restrict__ inv,
                                              float* __restrict__ out){
    int tile = blockIdx.x & 63; int b = blockIdx.x >> 6;
    int l0 = tile * 64;
    __shared__ float t0[CC * 65];
    __shared__ int invs[64];
    if (threadIdx.x < 64) invs[threadIdx.x] = inv[b*LL + l0 + threadIdx.x];
    __syncthreads();
    const float* y0p = ys + (size_t)(b*KK + 0) * CC * LL;
    const float* y1p = ys + (size_t)(b*KK + 1) * CC * LL;
    const float* y2p = ys + (size_t)(b*KK + 2) * CC * LL;
    for (int it = 0; it < 24; it++){
        int e = it * 256 + threadIdx.x;
        int li = e & 63; int c = e >> 6;
        int l = l0 + li;
        float v = y0p[(size_t)c*LL + l] + y1p[(size_t)c*LL + (LL-1-l)] + y2p[(size_t)c*LL + invs[li]];
        t0[c*65 + li] = v * (1.0f/3.0f);
    }
    __syncthreads();
    for (int it = 0; it < 24; it++){
        int e = it * 256 + threadIdx.x;
        int c = e % CC; int li = e / CC;
        out[((size_t)b*LL + l0 + li) * CC + c] = t0[c*65 + li];
    }
}

extern "C" void kernel_launch(void* const* d_in, const int* in_sizes, int n_in,
                              void* d_out, int out_size, void* d_ws, size_t ws_size,
                              hipStream_t stream){
    const float* x    = (const float*)d_in[0];
    const float* xpw  = (const float*)d_in[1];
    const float* dtw  = (const float*)d_in[2];
    const float* dtb  = (const float*)d_in[3];
    const float* Alog = (const float*)d_in[4];
    const float* Ds   = (const float*)d_in[5];
    const float* c1w  = (const float*)d_in[6];
    const float* c1b  = (const float*)d_in[7];
    const float* ca1w = (const float*)d_in[8];
    const float* ca1b = (const float*)d_in[9];
    const float* ca2w = (const float*)d_in[10];
    const float* ca2b = (const float*)d_in[11];
    const float* lng  = (const float*)d_in[12];
    const float* lnb  = (const float*)d_in[13];
    const float* c2w  = (const float*)d_in[14];
    const float* rpet = (const float*)d_in[15];
    float* out = (float*)d_out;

    float* ws   = (float*)d_ws;
    float* xc   = ws;                      // 384
    float* ca   = xc + 384;                // 384
    float* x1   = ca + 384;                // B*C*L = 1572864
    float* rpe  = x1 + (size_t)BB*CC*LL;   // C*L = 393216
    float* posy = rpe + (size_t)CC*LL;     // B*L
    float* posx = posy + (size_t)BB*LL;
    float* path = posx + (size_t)BB*LL;
    float* xd   = path + (size_t)BB*LL;    // B*C*L
    int*   idx  = (int*)(xd + (size_t)BB*CC*LL);   // B*L ints
    int*   inv  = idx + (size_t)BB*LL;             // B*L ints
    float* u2   = (float*)(inv + (size_t)BB*LL);   // B*C*L
    float* dtA  = u2 + (size_t)BB*CC*LL;           // B*K*C*L = 4718592
    float* Bst  = dtA + (size_t)BB*KK*CC*LL;       // B*K*L*N = 786432
    float* Cst  = Bst + (size_t)BB*KK*LL*NN;
    float* ysA  = Cst + (size_t)BB*KK*LL*NN;       // B*K*C*L

    k_mean  <<<BB*CC, 256, 0, stream>>>(x, xc);
    k_ca    <<<BB, 128, 0, stream>>>(xc, ca1w, ca1b, ca2w, ca2b, ca);
    k_conv  <<<(BB*CC*LL)/256, 256, 0, stream>>>(x, c1w, c1b, ca, x1);
    k_rpe   <<<(CC*LL)/256, 256, 0, stream>>>(rpet, rpe);
    k_off   <<<BB*64, 256, 0, stream>>>(x1, lng, lnb, c2w, posy, posx, path);
    k_sort  <<<BB, 1024, 0, stream>>>(path, idx, inv);
    k_sample<<<(BB*CC*LL)/256, 256, 0, stream>>>(x, rpe, posy, posx, xd);
    k_proj  <<<BB*KK*64, 192, 0, stream>>>(x, xd, idx, xpw, dtw, dtb, u2, dtA, Bst, Cst);
    k_scan_all<<<KK*BB*CC, 512, 0, stream>>>(x, u2, dtA, Bst, Cst, Alog, Ds, ysA);
    k_comb  <<<BB*64, 256, 0, stream>>>(ysA, inv, out);
}

// Round 11
// 349.393 us; speedup vs baseline: 1.5640x; 1.0061x over previous
//
#include <hip/hip_runtime.h>

#define BB 4
#define CC 96
#define HH 64
#define WW 64
#define LL 4096
#define KK 3
#define RR 6
#define NN 16

__device__ __forceinline__ float geluf(float x){
    return 0.5f * x * (1.0f + erff(x * 0.70710678118654752f));
}
__device__ __forceinline__ float softplusf(float x){
    return fmaxf(x, 0.0f) + log1pf(expf(-fabsf(x)));
}
__device__ __forceinline__ float sigmoidf(float x){
    return 1.0f / (1.0f + expf(-x));
}

// ---------------- Kernel A: per-(b,c) spatial mean ----------------
__global__ __launch_bounds__(256) void k_mean(const float* __restrict__ x, float* __restrict__ xc){
    int bc = blockIdx.x; // 0..B*C-1
    const float* p = x + (size_t)bc * LL;
    float s = 0.f;
    for (int i = threadIdx.x; i < LL; i += 256) s += p[i];
    __shared__ float red[256];
    red[threadIdx.x] = s; __syncthreads();
    for (int st = 128; st > 0; st >>= 1){
        if (threadIdx.x < st) red[threadIdx.x] += red[threadIdx.x + st];
        __syncthreads();
    }
    if (threadIdx.x == 0) xc[bc] = red[0] * (1.0f / LL);
}

// ---------------- Kernel B: channel-attention MLP ----------------
__global__ __launch_bounds__(128) void k_ca(const float* __restrict__ xc,
                     const float* __restrict__ w1, const float* __restrict__ b1,
                     const float* __restrict__ w2, const float* __restrict__ b2,
                     float* __restrict__ ca){
    int b = blockIdx.x;
    int t = threadIdx.x;
    __shared__ float hid[CC/16];
    if (t < CC/16){
        float a = b1[t];
        for (int d = 0; d < CC; d++) a += w1[t*CC + d] * xc[b*CC + d];
        hid[t] = geluf(a);
    }
    __syncthreads();
    if (t < CC){
        float a = b2[t];
        #pragma unroll
        for (int i = 0; i < CC/16; i++) a += w2[t*(CC/16) + i] * hid[i];
        ca[b*CC + t] = sigmoidf(a);
    }
}

// ---------------- Kernel C: depthwise 9x9 conv + bias, scaled by ca ----------------
__global__ __launch_bounds__(256) void k_conv(const float* __restrict__ x, const float* __restrict__ w,
                       const float* __restrict__ bias, const float* __restrict__ ca,
                       float* __restrict__ x1){
    int gid = blockIdx.x * 256 + threadIdx.x; // B*C*L
    int l = gid & (LL-1); int bc = gid >> 12;
    int c = bc % CC; int b = bc / CC;
    int h = l >> 6, wq = l & 63;
    const float* xp = x + (size_t)bc * LL;
    const float* wp = w + c * 81;
    float acc = 0.f;
    #pragma unroll
    for (int ky = 0; ky < 9; ky++){
        int yy = h + ky - 4;
        if (yy < 0 || yy >= HH) continue;
        #pragma unroll
        for (int kx = 0; kx < 9; kx++){
            int xx = wq + kx - 4;
            if (xx < 0 || xx >= WW) continue;
            acc += xp[yy*WW + xx] * wp[ky*9 + kx];
        }
    }
    x1[gid] = (acc + bias[c]) * ca[b*CC + c];
}

// ---------------- Kernel D: rpe resize 7x7 -> 64x64 (b-independent) ----------------
__global__ __launch_bounds__(256) void k_rpe(const float* __restrict__ t, float* __restrict__ out){
    int gid = blockIdx.x * 256 + threadIdx.x; // C*L
    int l = gid & (LL-1); int c = gid >> 12;
    int h = l >> 6, w = l & 63;
    float sy = fmaxf((h + 0.5f) * (7.0f/64.0f) - 0.5f, 0.f);
    float sx = fmaxf((w + 0.5f) * (7.0f/64.0f) - 0.5f, 0.f);
    int y0 = (int)floorf(sy); int x0 = (int)floorf(sx);
    float wy = sy - (float)y0, wx = sx - (float)x0;
    int y1 = min(y0 + 1, 6), x1i = min(x0 + 1, 6);
    const float* tp = t + c * 49;
    float r0 = tp[y0*7 + x0] * (1.f - wy) + tp[y1*7 + x0] * wy;
    float r1 = tp[y0*7 + x1i] * (1.f - wy) + tp[y1*7 + x1i] * wy;
    out[gid] = r0 * (1.f - wx) + r1 * wx;
}

// ---------------- Kernel E: LayerNorm(C) + GELU + 1x1 conv, tiled ----------------
__global__ __launch_bounds__(256) void k_off(const float* __restrict__ x1,
                      const float* __restrict__ g, const float* __restrict__ bta,
                      const float* __restrict__ w2,
                      float* __restrict__ posy, float* __restrict__ posx, float* __restrict__ path){
    int blk = blockIdx.x;            // b*64 + ltile
    int ltile = blk & 63; int b = blk >> 6;
    int lane = threadIdx.x & 63;
    int wg = threadIdx.x >> 6;       // 0..3
    int l = ltile * 64 + lane;
    const float* p = x1 + (size_t)b * CC * LL + l;
    float v[24];
    float s = 0.f, ss = 0.f;
    #pragma unroll
    for (int j = 0; j < 24; j++){
        float t = p[(size_t)(wg*24 + j) * LL];
        v[j] = t; s += t; ss += t*t;
    }
    __shared__ float ls[4][64], lss[4][64];
    ls[wg][lane] = s; lss[wg][lane] = ss;
    __syncthreads();
    s  = ls[0][lane]  + ls[1][lane]  + ls[2][lane]  + ls[3][lane];
    ss = lss[0][lane] + lss[1][lane] + lss[2][lane] + lss[3][lane];
    float m = s * (1.0f/CC);
    float rstd = rsqrtf(ss*(1.0f/CC) - m*m + 1e-5f);
    float a0 = 0.f, a1 = 0.f, a2 = 0.f;
    #pragma unroll
    for (int j = 0; j < 24; j++){
        int c = wg*24 + j;
        float xn = (v[j]-m)*rstd*g[c] + bta[c];
        float xg = geluf(xn);
        a0 = fmaf(w2[c],      xg, a0);
        a1 = fmaf(w2[CC+c],   xg, a1);
        a2 = fmaf(w2[2*CC+c], xg, a2);
    }
    __shared__ float la[3][4][64];
    la[0][wg][lane] = a0; la[1][wg][lane] = a1; la[2][wg][lane] = a2;
    __syncthreads();
    if (wg < 3){
        float a = la[wg][0][lane] + la[wg][1][lane] + la[wg][2][lane] + la[wg][3][lane];
        int h = l >> 6, w = l & 63;
        if (wg == 0)      posy[b*LL + l] = tanhf(a)*(1.0f/63.0f) + ((2*h+1)*(1.0f/63.0f) - 1.0f);
        else if (wg == 1) posx[b*LL + l] = tanhf(a)*(1.0f/63.0f) + ((2*w+1)*(1.0f/63.0f) - 1.0f);
        else              path[b*LL + l] = tanhf(a) + ((l + 0.5f)*(2.0f/4095.0f) - 1.0f);
    }
}

// ---------------- Kernel F: hybrid register/shuffle/LDS stable bitonic argsort ----------------
typedef unsigned long long u64s;
__device__ __forceinline__ u64s shflx64(u64s x, int m){
    int lo = __shfl_xor((int)(unsigned)x, m);
    int hi = __shfl_xor((int)(unsigned)(x >> 32), m);
    return ((u64s)(unsigned)hi << 32) | (unsigned)lo;
}
__device__ __forceinline__ void cex(u64s& a, u64s& b, bool up){
    u64s mn = a < b ? a : b;
    u64s mx = a < b ? b : a;
    a = up ? mn : mx;
    b = up ? mx : mn;
}
__global__ __launch_bounds__(1024) void k_sort(const float* __restrict__ path,
                                               int* __restrict__ idx, int* __restrict__ inv){
    int b = blockIdx.x;
    int t = threadIdx.x;
    __shared__ u64s lds[LL];
    u64s v[4];
    #pragma unroll
    for (int r = 0; r < 4; r++){
        int e = t*4 + r;
        unsigned u = __float_as_uint(path[b*LL + e]);
        u ^= (u >> 31) ? 0xFFFFFFFFu : 0x80000000u;   // monotonic float->uint
        v[r] = ((u64s)u << 32) | (unsigned)e;
    }
    for (int kk = 2; kk <= LL; kk <<= 1){
        for (int j = kk >> 1; j > 0; j >>= 1){
            if (j >= 256){
                __syncthreads();
                #pragma unroll
                for (int r = 0; r < 4; r++) lds[t*4 + r] = v[r];
                __syncthreads();
                #pragma unroll
                for (int r = 0; r < 4; r++){
                    int e = t*4 + r;
                    u64s pv = lds[e ^ j];
                    bool up    = ((e & kk) == 0);
                    bool lower = ((e & j) == 0);
                    u64s mn = v[r] < pv ? v[r] : pv;
                    u64s mx = v[r] < pv ? pv : v[r];
                    v[r] = (up == lower) ? mn : mx;
                }
            } else if (j >= 4){
                int m = j >> 2;
                #pragma unroll
                for (int r = 0; r < 4; r++){
                    u64s pv = shflx64(v[r], m);
                    bool up    = (((t*4 + r) & kk) == 0);
                    bool lower = ((t & m) == 0);
                    u64s mn = v[r] < pv ? v[r] : pv;
                    u64s mx = v[r] < pv ? pv : v[r];
                    v[r] = (up == lower) ? mn : mx;
                }
            } else if (j == 2){
                bool up = (((t*4) & kk) == 0);
                cex(v[0], v[2], up);
                cex(v[1], v[3], up);
            } else { // j == 1
                if (kk == 2){
                    cex(v[0], v[1], true);
                    cex(v[2], v[3], false);
                } else {
                    bool up = (((t*4) & kk) == 0);
                    cex(v[0], v[1], up);
                    cex(v[2], v[3], up);
                }
            }
        }
    }
    #pragma unroll
    for (int r = 0; r < 4; r++){
        int e = t*4 + r;
        int id = (int)(unsigned)(v[r] & 0xFFFFFFFFu);
        idx[b*LL + e] = id;
        inv[b*LL + id] = e;
    }
}

// ---------------- bilinear sample, zero padding ----------------
__device__ __forceinline__ float bilin0(const float* __restrict__ img, float gx, float gy){
    float fx = (gx + 1.f) * 31.5f;   // (W-1)/2 = 31.5
    float fy = (gy + 1.f) * 31.5f;
    float x0f = floorf(fx), y0f = floorf(fy);
    float wx = fx - x0f, wy = fy - y0f;
    int x0 = (int)x0f, y0 = (int)y0f;
    float acc = 0.f;
    bool vx0 = (x0 >= 0) & (x0 < WW), vx1 = (x0+1 >= 0) & (x0+1 < WW);
    bool vy0 = (y0 >= 0) & (y0 < HH), vy1 = (y0+1 >= 0) & (y0+1 < HH);
    if (vy0 & vx0) acc += img[y0*WW + x0]       * (1.f-wx) * (1.f-wy);
    if (vy0 & vx1) acc += img[y0*WW + x0+1]     * wx       * (1.f-wy);
    if (vy1 & vx0) acc += img[(y0+1)*WW + x0]   * (1.f-wx) * wy;
    if (vy1 & vx1) acc += img[(y0+1)*WW + x0+1] * wx       * wy;
    return acc;
}

// ---------------- Kernel S: x grid-sample + rpe grid-sample -> xd ----------------
__global__ __launch_bounds__(256) void k_sample(const float* __restrict__ x, const float* __restrict__ rpe,
                         const float* __restrict__ posy, const float* __restrict__ posx,
                         float* __restrict__ xd){
    int gid = blockIdx.x * 256 + threadIdx.x; // B*C*L
    int l = gid & (LL-1); int bc = gid >> 12;
    int b = bc / CC; int c = bc % CC;
    float gy = posy[b*LL + l], gx = posx[b*LL + l];
    float v = bilin0(x + (size_t)bc * LL, gx, gy);
    int h = l >> 6, w = l & 63;
    float ky = h * (128.0f/3969.0f) - 1.0f;  // linspace(0,64,64)/63*2-1
    float kx = w * (128.0f/3969.0f) - 1.0f;
    float v2 = bilin0(rpe + (size_t)c * LL, (kx - gx) * 0.5f, (ky - gy) * 0.5f);
    xd[gid] = v + v2;
}

// ---------------- Kernel G: projection, 3-wave output split + shared v in LDS ----------------
__global__ __launch_bounds__(192, 1) void k_proj(const float* __restrict__ x, const float* __restrict__ xd,
    const int* __restrict__ indices, const float* __restrict__ xpw, const float* __restrict__ dtw,
    const float* __restrict__ dtb, float* __restrict__ u2, float* __restrict__ dt,
    float* __restrict__ Bst, float* __restrict__ Cst){
    int blk = blockIdx.x;          // B*K*64 blocks
    int ltile = blk & 63; int bk = blk >> 6;
    int k = bk % KK; int b = bk / KK;
    int lane = threadIdx.x & 63;
    int w = threadIdx.x >> 6;      // 0..2
    const float* __restrict__ Wk = xpw + k*38*CC;
    int l = ltile * 64 + lane;
    int srcl = (k == 0) ? l : (k == 1 ? (LL-1-l) : indices[b*LL + l]);
    const float* xp = (k == 2 ? xd : x) + (size_t)b * CC * LL + srcl;

    __shared__ float vsh[CC*64];   // 24 KB
    #pragma unroll
    for (int j = 0; j < 32; j++){
        int d = w*32 + j;
        vsh[d*64 + lane] = xp[(size_t)d * LL];
    }
    __syncthreads();

    if (w == 0){
        float acc[RR];
        #pragma unroll
        for (int i = 0; i < RR; i++) acc[i] = 0.f;
        for (int d = 0; d < CC; d++){
            float vv = vsh[d*64 + lane];
            #pragma unroll
            for (int i = 0; i < RR; i++) acc[i] = fmaf(Wk[i*CC + d], vv, acc[i]);
        }
        const float* __restrict__ Dw = dtw + k*CC*RR;
        const float* __restrict__ Db = dtb + k*CC;
        float* dtp = dt + (size_t)bk * CC * LL + l;
        #pragma unroll 8
        for (int d = 0; d < CC; d++){
            float sdt = Db[d];
            #pragma unroll
            for (int r = 0; r < RR; r++) sdt = fmaf(acc[r], Dw[d*RR + r], sdt);
            dtp[(size_t)d * LL] = softplusf(sdt);
        }
    } else if (w == 1){
        float acc[NN];
        #pragma unroll
        for (int i = 0; i < NN; i++) acc[i] = 0.f;
        for (int d = 0; d < CC; d++){
            float vv = vsh[d*64 + lane];
            #pragma unroll
            for (int i = 0; i < NN; i++) acc[i] = fmaf(Wk[(RR + i)*CC + d], vv, acc[i]);
        }
        size_t base = ((size_t)bk * LL + l) * NN;
        #pragma unroll
        for (int q = 0; q < 4; q++){
            float4 o; o.x = acc[q*4]; o.y = acc[q*4+1]; o.z = acc[q*4+2]; o.w = acc[q*4+3];
            *(float4*)(Bst + base + q*4) = o;
        }
    } else {
        float acc[NN];
        #pragma unroll
        for (int i = 0; i < NN; i++) acc[i] = 0.f;
        for (int d = 0; d < CC; d++){
            float vv = vsh[d*64 + lane];
            #pragma unroll
            for (int i = 0; i < NN; i++) acc[i] = fmaf(Wk[(RR + NN + i)*CC + d], vv, acc[i]);
        }
        size_t base = ((size_t)bk * LL + l) * NN;
        #pragma unroll
        for (int q = 0; q < 4; q++){
            float4 o; o.x = acc[q*4]; o.y = acc[q*4+1]; o.z = acc[q*4+2]; o.w = acc[q*4+3];
            *(float4*)(Cst + base + q*4) = o;
        }
        if (k == 2){
            float* up = u2 + (size_t)b * CC * LL + l;
            #pragma unroll 8
            for (int d = 0; d < CC; d++) up[(size_t)d * LL] = vsh[d*64 + lane];
        }
    }
}

// ---------------- Kernel H: merged selective scan ----------------
// Block = one (bk,d), 512 thr = 128 segments x 4 n-groups; segment = 32 steps.
// Phase 1 caches scan-ordered dt in LDS (padded rows, 2-way bank alias = free).
// Phase 2: per-wave shuffle scan of the (A,B) monoid over 128 segments (2 chains
// per wave, 2 segments per lane) -- replaces the 16-thread serial LDS loop.
// Phase 3: dt from LDS, u re-read from global.
#define SEG 128        // segments
#define TL 32          // steps per segment
#define SROW 17        // padded row stride for sA/sB (words)
#define DROW 36        // padded row stride for sdt (words), 16B-aligned
template<int KIND>
__device__ __forceinline__ void scan_body(int b, int d, const float* __restrict__ usrc,
    const float* __restrict__ dt, const float* __restrict__ Bst, const float* __restrict__ Cst,
    const float* __restrict__ Alog, const float* __restrict__ Ds, float* __restrict__ ys,
    float* sA, float* sB, float* sdt){
    int bk = b * KK + KIND;
    int tid = threadIdx.x;
    int ng = tid & 3;          // n = 4*ng + j
    int seg = tid >> 2;        // 0..127
    int t0 = seg * TL;

    const float4 A4 = *(const float4*)(Alog + (KIND*CC + d)*NN + 4*ng);
    float A[4] = { -__expf(A4.x), -__expf(A4.y), -__expf(A4.z), -__expf(A4.w) };
    float Dv = Ds[KIND*CC + d];

    const float* dtp = dt + ((size_t)bk * CC + d) * LL + t0;
    const float* ub = (KIND == 1)
        ? usrc + ((size_t)b*CC + d) * LL + (LL-4-t0)
        : usrc + ((size_t)b*CC + d) * LL + t0;
    const float* Bp = Bst + ((size_t)bk * LL + t0) * NN + 4*ng;
    const float* Cp = Cst + ((size_t)bk * LL + t0) * NN + 4*ng;
    float* yp = ys + ((size_t)bk * CC + d) * LL + t0;

    // Phase 1: local segment scan from h=0; stage dt (scan order) into LDS
    float Ap[4] = {1.f,1.f,1.f,1.f}, h[4] = {0.f,0.f,0.f,0.f};
    for (int t = 0; t < TL; t += 4){
        float4 dq = *(const float4*)(dtp + t);
        float4 uq = (KIND == 1) ? *(const float4*)(ub - t) : *(const float4*)(ub + t);
        float dd[4] = {dq.x, dq.y, dq.z, dq.w};
        float uu[4];
        if (KIND == 1){ uu[0]=uq.w; uu[1]=uq.z; uu[2]=uq.y; uu[3]=uq.x; }
        else          { uu[0]=uq.x; uu[1]=uq.y; uu[2]=uq.z; uu[3]=uq.w; }
        if (ng == 0) *(float4*)(sdt + seg*DROW + t) = dq;
        #pragma unroll
        for (int i = 0; i < 4; i++){
            float4 Bq = *(const float4*)(Bp + (t+i)*NN);
            float du = dd[i] * uu[i];
            float bb[4] = {Bq.x, Bq.y, Bq.z, Bq.w};
            #pragma unroll
            for (int j = 0; j < 4; j++){
                float a = __expf(dd[i] * A[j]);
                Ap[j] *= a;
                h[j] = fmaf(a, h[j], du * bb[j]);
            }
        }
    }

    // Phase 2: per-wave shuffle scan over 128 segments (exclusive carries)
    #pragma unroll
    for (int j = 0; j < 4; j++){
        sA[seg*SROW + 4*ng + j] = Ap[j];
        sB[seg*SROW + 4*ng + j] = h[j];
    }
    __syncthreads();
    {
        int wv = tid >> 6;         // 0..7
        int lane = tid & 63;
        #pragma unroll
        for (int nn = 0; nn < 2; nn++){
            int n = 2*wv + nn;
            float a1 = sA[(2*lane)*SROW + n],   b1 = sB[(2*lane)*SROW + n];
            float a2 = sA[(2*lane+1)*SROW + n], b2 = sB[(2*lane+1)*SROW + n];
            float ca = a1 * a2;
            float cb = fmaf(a2, b1, b2);
            #pragma unroll
            for (int off = 1; off < 64; off <<= 1){
                float ta = __shfl_up(ca, off);
                float tb = __shfl_up(cb, off);
                if (lane >= off){
                    cb = fmaf(ca, tb, cb);
                    ca *= ta;
                }
            }
            float cb_prev = __shfl_up(cb, 1);
            if (lane == 0) cb_prev = 0.f;
            // write exclusive carries (reuse sA as carry buffer; columns are wave-private)
            sA[(2*lane)*SROW + n]   = cb_prev;
            sA[(2*lane+1)*SROW + n] = fmaf(a1, cb_prev, b1);
        }
    }
    __syncthreads();
    float hc[4];
    #pragma unroll
    for (int j = 0; j < 4; j++) hc[j] = sA[seg*SROW + 4*ng + j];

    // Phase 3: replay with carry-in; dt from LDS, u from global
    for (int t = 0; t < TL; t += 4){
        float4 dq = *(const float4*)(sdt + seg*DROW + t);
        float4 uq = (KIND == 1) ? *(const float4*)(ub - t) : *(const float4*)(ub + t);
        float dd[4] = {dq.x, dq.y, dq.z, dq.w};
        float uu[4];
        if (KIND == 1){ uu[0]=uq.w; uu[1]=uq.z; uu[2]=uq.y; uu[3]=uq.x; }
        else          { uu[0]=uq.x; uu[1]=uq.y; uu[2]=uq.z; uu[3]=uq.w; }
        float yo[4];
        #pragma unroll
        for (int i = 0; i < 4; i++){
            float4 Bq = *(const float4*)(Bp + (t+i)*NN);
            float4 Cq = *(const float4*)(Cp + (t+i)*NN);
            float du = dd[i] * uu[i];
            float bb[4] = {Bq.x, Bq.y, Bq.z, Bq.w};
            float cc[4] = {Cq.x, Cq.y, Cq.z, Cq.w};
            float p = 0.f;
            #pragma unroll
            for (int j = 0; j < 4; j++){
                float a = __expf(dd[i] * A[j]);
                hc[j] = fmaf(a, hc[j], du * bb[j]);
                p = fmaf(hc[j], cc[j], p);
            }
            p += __shfl_xor(p, 1);
            p += __shfl_xor(p, 2);
            yo[i] = fmaf(uu[i], Dv, p);
        }
        if (ng == 0){
            float4 o; o.x = yo[0]; o.y = yo[1]; o.z = yo[2]; o.w = yo[3];
            *(float4*)(yp + t) = o;
        }
    }
}

__global__ __launch_bounds__(512) void k_scan_all(const float* __restrict__ x, const float* __restrict__ u2,
    const float* __restrict__ dt, const float* __restrict__ Bst, const float* __restrict__ Cst,
    const float* __restrict__ Alog, const float* __restrict__ Ds, float* __restrict__ ys){
    __shared__ float sA[SEG*SROW];
    __shared__ float sB[SEG*SROW];
    __shared__ float sdt[SEG*DROW];
    int blk = blockIdx.x;            // KK*BB*CC
    int k = blk / (BB*CC);
    int r = blk % (BB*CC);
    int d = r % CC; int b = r / CC;
    if (k == 0)      scan_body<0>(b, d, x,  dt, Bst, Cst, Alog, Ds, ys, sA, sB, sdt);
    else if (k == 1) scan_body<1>(b, d, x,  dt, Bst, Cst, Alog, Ds, ys, sA, sB, sdt);
    else             scan_body<2>(b, d, u2, dt, Bst, Cst, Alog, Ds, ys, sA, sB, sdt);
}

// ---------------- Kernel I: combine 3 paths + transpose to (B,L,C) ----------------
__global__ __launch_bounds__(256) void k_comb(const float* __restrict__ ys, const int* __restrict__ inv,
                                              float* __restrict__ out){
    int tile = blockIdx.x & 63; int b = blockIdx.x >> 6;
    int l0 = tile * 64;
    __shared__ float t0[CC * 65];
    __shared__ int invs[64];
    if (threadIdx.x < 64) invs[threadIdx.x] = inv[b*LL + l0 + threadIdx.x];
    __syncthreads();
    const float* y0p = ys + (size_t)(b*KK + 0) * CC * LL;
    const float* y1p = ys + (size_t)(b*KK + 1) * CC * LL;
    const float* y2p = ys + (size_t)(b*KK + 2) * CC * LL;
    for (int it = 0; it < 24; it++){
        int e = it * 256 + threadIdx.x;
        int li = e & 63; int c = e >> 6;
        int l = l0 + li;
        float v = y0p[(size_t)c*LL + l] + y1p[(size_t)c*LL + (LL-1-l)] + y2p[(size_t)c*LL + invs[li]];
        t0[c*65 + li] = v * (1.0f/3.0f);
    }
    __syncthreads();
    for (int it = 0; it < 24; it++){
        int e = it * 256 + threadIdx.x;
        int c = e % CC; int li = e / CC;
        out[((size_t)b*LL + l0 + li) * CC + c] = t0[c*65 + li];
    }
}

extern "C" void kernel_launch(void* const* d_in, const int* in_sizes, int n_in,
                              void* d_out, int out_size, void* d_ws, size_t ws_size,
                              hipStream_t stream){
    const float* x    = (const float*)d_in[0];
    const float* xpw  = (const float*)d_in[1];
    const float* dtw  = (const float*)d_in[2];
    const float* dtb  = (const float*)d_in[3];
    const float* Alog = (const float*)d_in[4];
    const float* Ds   = (const float*)d_in[5];
    const float* c1w  = (const float*)d_in[6];
    const float* c1b  = (const float*)d_in[7];
    const float* ca1w = (const float*)d_in[8];
    const float* ca1b = (const float*)d_in[9];
    const float* ca2w = (const float*)d_in[10];
    const float* ca2b = (const float*)d_in[11];
    const float* lng  = (const float*)d_in[12];
    const float* lnb  = (const float*)d_in[13];
    const float* c2w  = (const float*)d_in[14];
    const float* rpet = (const float*)d_in[15];
    float* out = (float*)d_out;

    float* ws   = (float*)d_ws;
    float* xc   = ws;                      // 384
    float* ca   = xc + 384;                // 384
    float* x1   = ca + 384;                // B*C*L = 1572864
    float* rpe  = x1 + (size_t)BB*CC*LL;   // C*L = 393216
    float* posy = rpe + (size_t)CC*LL;     // B*L
    float* posx = posy + (size_t)BB*LL;
    float* path = posx + (size_t)BB*LL;
    float* xd   = path + (size_t)BB*LL;    // B*C*L
    int*   idx  = (int*)(xd + (size_t)BB*CC*LL);   // B*L ints
    int*   inv  = idx + (size_t)BB*LL;             // B*L ints
    float* u2   = (float*)(inv + (size_t)BB*LL);   // B*C*L
    float* dtA  = u2 + (size_t)BB*CC*LL;           // B*K*C*L = 4718592
    float* Bst  = dtA + (size_t)BB*KK*CC*LL;       // B*K*L*N = 786432
    float* Cst  = Bst + (size_t)BB*KK*LL*NN;
    float* ysA  = Cst + (size_t)BB*KK*LL*NN;       // B*K*C*L

    k_mean  <<<BB*CC, 256, 0, stream>>>(x, xc);
    k_ca    <<<BB, 128, 0, stream>>>(xc, ca1w, ca1b, ca2w, ca2b, ca);
    k_conv  <<<(BB*CC*LL)/256, 256, 0, stream>>>(x, c1w, c1b, ca, x1);
    k_rpe   <<<(CC*LL)/256, 256, 0, stream>>>(rpet, rpe);
    k_off   <<<BB*64, 256, 0, stream>>>(x1, lng, lnb, c2w, posy, posx, path);
    k_sort  <<<BB, 1024, 0, stream>>>(path, idx, inv);
    k_sample<<<(BB*CC*LL)/256, 256, 0, stream>>>(x, rpe, posy, posx, xd);
    k_proj  <<<BB*KK*64, 192, 0, stream>>>(x, xd, idx, xpw, dtw, dtb, u2, dtA, Bst, Cst);
    k_scan_all<<<KK*BB*CC, 512, 0, stream>>>(x, u2, dtA, Bst, Cst, Alog, Ds, ysA);
    k_comb  <<<BB*64, 256, 0, stream>>>(ysA, inv, out);
}